// Round 5
// baseline (742.641 us; speedup 1.0000x reference)
//
#include <hip/hip_runtime.h>
#include <math.h>

#define B_SZ 2
#define SEQ  1024
#define DM   1024
#define DI   2048
#define NST  16
#define RNK  64
#define XPD  96            // RNK + 2*NST
#define M_TOT (B_SZ*SEQ)   // 2048
#define NC   32            // scan chunks
#define LC   (SEQ/NC)      // 32 steps per chunk
#define NCH  65536         // total chains = B_SZ*DI*NST

typedef unsigned short ushort_t;
typedef __attribute__((ext_vector_type(8))) short short8;   // 8 bf16 = 4 VGPRs
typedef __attribute__((ext_vector_type(4))) float f32x4;

#if __has_builtin(__builtin_amdgcn_exp2f)
#define EXP2F __builtin_amdgcn_exp2f
#else
#define EXP2F exp2f
#endif
#define LOG2E 1.44269504f

__device__ __forceinline__ ushort_t f2bf(float f) {
    unsigned u = __float_as_uint(f);
    u += 0x7fff + ((u >> 16) & 1);           // round-to-nearest-even
    return (ushort_t)(u >> 16);
}

// ---------------------------------------------------------------------------
// fp32 -> bf16 bulk convert (n multiple of 1024; float4 per thread)
// ---------------------------------------------------------------------------
__global__ __launch_bounds__(256)
void f32_to_bf16(const float* __restrict__ in, ushort_t* __restrict__ out)
{
    int i = blockIdx.x * 256 + threadIdx.x;
    float4 v = ((const float4*)in)[i];
    ushort4 o;
    o.x = f2bf(v.x); o.y = f2bf(v.y); o.z = f2bf(v.z); o.w = f2bf(v.w);
    ((ushort4*)out)[i] = o;
}

// ---------------------------------------------------------------------------
// bf16 MFMA NT GEMM: D[M,N] = scale * (A[M,K] * W[N,K]^T) (+= if accum)
// ---------------------------------------------------------------------------
#define BK   64
#define LDSP 72   // padded LDS row stride (bf16 elems)

template<int BM, int BN>
__global__ __launch_bounds__(256)
void gemm_mfma(const ushort_t* __restrict__ A, const ushort_t* __restrict__ W,
               float* __restrict__ D, int M, int N, int K,
               int flipA, int flipOut, float scale, int accum)
{
    __shared__ __align__(16) ushort_t As[BM * LDSP];
    __shared__ __align__(16) ushort_t Ws[BN * LDSP];
    const int t    = threadIdx.x;
    const int lane = t & 63;
    const int wave = t >> 6;
    const int wr   = (wave >> 1) * (BM / 2);
    const int wc   = (wave & 1) * (BN / 2);
    constexpr int MT  = BM / 32;
    constexpr int NTW = BN / 32;

    f32x4 acc[MT][NTW] = {};

    const int m0 = blockIdx.y * BM;
    const int n0 = blockIdx.x * BN;
    const int srow = t >> 3;
    const int scol = (t & 7) << 3;

    for (int k0 = 0; k0 < K; k0 += BK) {
#pragma unroll
        for (int it = 0; it < BM / 32; it++) {
            int r = it * 32 + srow;
            int m = m0 + r;
            int arow = m;
            if (flipA) { int b = m >> 10, l = m & 1023; arow = (b << 10) + (1023 - l); }
            short8 v = *(const short8*)(A + (size_t)arow * K + k0 + scol);
            *(short8*)(&As[r * LDSP + scol]) = v;
        }
#pragma unroll
        for (int it = 0; it < BN / 32; it++) {
            int r = it * 32 + srow;
            int wn = n0 + r;
            short8 v = {};
            if (wn < N) v = *(const short8*)(W + (size_t)wn * K + k0 + scol);
            *(short8*)(&Ws[r * LDSP + scol]) = v;
        }
        __syncthreads();
#pragma unroll
        for (int kk = 0; kk < 2; kk++) {
            const int kc = kk * 32 + ((lane >> 4) << 3);
            short8 af[MT], bfr[NTW];
#pragma unroll
            for (int i = 0; i < MT; i++)
                af[i] = *(const short8*)(&As[(wr + i * 16 + (lane & 15)) * LDSP + kc]);
#pragma unroll
            for (int j = 0; j < NTW; j++)
                bfr[j] = *(const short8*)(&Ws[(wc + j * 16 + (lane & 15)) * LDSP + kc]);
#pragma unroll
            for (int i = 0; i < MT; i++)
#pragma unroll
                for (int j = 0; j < NTW; j++)
                    acc[i][j] = __builtin_amdgcn_mfma_f32_16x16x32_bf16(
                        af[i], bfr[j], acc[i][j], 0, 0, 0);
        }
        __syncthreads();
    }

#pragma unroll
    for (int i = 0; i < MT; i++) {
#pragma unroll
        for (int r = 0; r < 4; r++) {
            int m = m0 + wr + i * 16 + ((lane >> 4) << 2) + r;
            int b = m >> 10, l = m & 1023;
            int mo = flipOut ? ((b << 10) + (1023 - l)) : m;
#pragma unroll
            for (int j = 0; j < NTW; j++) {
                int n = n0 + wc + j * 16 + (lane & 15);
                if (n < N) {
                    float v = scale * acc[i][j][r];
                    size_t idx = (size_t)mo * N + n;
                    if (accum) D[idx] += v; else D[idx] = v;
                }
            }
        }
    }
}

// ---------------------------------------------------------------------------
// delta = softplus(dt[M,64] * dtW[DI,64]^T + dtB) as single-K-tile MFMA GEMM.
// Stores result into du[m][n].x (packed {delta,u} float2 array).
// ---------------------------------------------------------------------------
__global__ __launch_bounds__(256)
void delta_gemm(const float* __restrict__ xdbl, const float* __restrict__ dtW,
                const float* __restrict__ dtB, float* __restrict__ duf)
{
    __shared__ __align__(16) ushort_t As[64 * LDSP];
    __shared__ __align__(16) ushort_t Ws[64 * LDSP];
    const int t    = threadIdx.x;
    const int lane = t & 63;
    const int wave = t >> 6;
    const int wr   = (wave >> 1) * 32;
    const int wc   = (wave & 1) * 32;

    const int m0 = blockIdx.y * 64;
    const int n0 = blockIdx.x * 64;
    const int srow = t >> 2;            // 0..63
    const int scol = (t & 3) << 4;      // 0,16,32,48

    {
        const float* ap = xdbl + (size_t)(m0 + srow) * XPD + scol;
        const float* wp = dtW  + (size_t)(n0 + srow) * RNK + scol;
        float4 a[4], w[4];
#pragma unroll
        for (int q = 0; q < 4; q++) { a[q] = ((const float4*)ap)[q]; w[q] = ((const float4*)wp)[q]; }
        ushort_t* as  = &As[srow * LDSP + scol];
        ushort_t* wsp = &Ws[srow * LDSP + scol];
#pragma unroll
        for (int q = 0; q < 16; q++) {
            as[q]  = f2bf(((const float*)a)[q]);
            wsp[q] = f2bf(((const float*)w)[q]);
        }
    }
    __syncthreads();

    f32x4 acc[2][2] = {};
#pragma unroll
    for (int kk = 0; kk < 2; kk++) {
        const int kc = kk * 32 + ((lane >> 4) << 3);
        short8 af[2], bfr[2];
#pragma unroll
        for (int i = 0; i < 2; i++)
            af[i] = *(const short8*)(&As[(wr + i * 16 + (lane & 15)) * LDSP + kc]);
#pragma unroll
        for (int j = 0; j < 2; j++)
            bfr[j] = *(const short8*)(&Ws[(wc + j * 16 + (lane & 15)) * LDSP + kc]);
#pragma unroll
        for (int i = 0; i < 2; i++)
#pragma unroll
            for (int j = 0; j < 2; j++)
                acc[i][j] = __builtin_amdgcn_mfma_f32_16x16x32_bf16(
                    af[i], bfr[j], acc[i][j], 0, 0, 0);
    }

#pragma unroll
    for (int j = 0; j < 2; j++) {
        int n = n0 + wc + j * 16 + (lane & 15);
        float bn = dtB[n];
#pragma unroll
        for (int i = 0; i < 2; i++) {
#pragma unroll
            for (int r = 0; r < 4; r++) {
                int m = m0 + wr + i * 16 + ((lane >> 4) << 2) + r;
                float v = acc[i][j][r] + bn;
                float sp = (v > 20.f) ? v : log1pf(__expf(v));
                duf[((size_t)m * DI + n) * 2] = sp;   // du.x
            }
        }
    }
}

// ---------------------------------------------------------------------------
// Depthwise causal conv(4) + bias + SiLU -> du.y (fp32) + ubf (bf16);
// also precomputes zs = silu(z) from the z half of xz.
// One thread = 4 channels of one (b,l).
// ---------------------------------------------------------------------------
__global__ __launch_bounds__(256)
void conv_silu(const float* __restrict__ xz, const float* __restrict__ convW,
               const float* __restrict__ convB, float* __restrict__ duf,
               ushort_t* __restrict__ ubf, float* __restrict__ zs)
{
    int idx = blockIdx.x * 256 + threadIdx.x;   // over M_TOT*DI/4
    int di  = (idx & (DI / 4 - 1)) << 2;
    int m   = idx >> 9;
    int b   = m >> 10, l = m & (SEQ - 1);
    float4 wv[4];
#pragma unroll
    for (int c = 0; c < 4; c++) wv[c] = *(const float4*)(convW + (di + c) * 4);
    float4 acc = *(const float4*)(convB + di);
#pragma unroll
    for (int j = 0; j < 4; j++) {
        int ll = l - 3 + j;
        if (ll >= 0) {
            float4 xv = *(const float4*)(xz + (size_t)(b * SEQ + ll) * (2 * DI) + di);
            acc.x += ((const float*)&wv[0])[j] * xv.x;
            acc.y += ((const float*)&wv[1])[j] * xv.y;
            acc.z += ((const float*)&wv[2])[j] * xv.z;
            acc.w += ((const float*)&wv[3])[j] * xv.w;
        }
    }
    float4 s;
    s.x = acc.x / (1.f + __expf(-acc.x));
    s.y = acc.y / (1.f + __expf(-acc.y));
    s.z = acc.z / (1.f + __expf(-acc.z));
    s.w = acc.w / (1.f + __expf(-acc.w));
    size_t base = ((size_t)m * DI + di) * 2;
    duf[base + 1] = s.x; duf[base + 3] = s.y;
    duf[base + 5] = s.z; duf[base + 7] = s.w;
    ushort4 o;
    o.x = f2bf(s.x); o.y = f2bf(s.y); o.z = f2bf(s.z); o.w = f2bf(s.w);
    *(ushort4*)(ubf + (size_t)m * DI + di) = o;

    // silu(z) for this (m, di..di+3)
    float4 zv = *(const float4*)(xz + (size_t)m * (2 * DI) + DI + di);
    float4 zo;
    zo.x = zv.x / (1.f + __expf(-zv.x));
    zo.y = zv.y / (1.f + __expf(-zv.y));
    zo.z = zv.z / (1.f + __expf(-zv.z));
    zo.w = zv.w / (1.f + __expf(-zv.w));
    *(float4*)(zs + (size_t)m * DI + di) = zo;
}

// ---------------------------------------------------------------------------
// Chunked selective scan, lane = d layout: each lane owns all 16 states of
// one d-chain (h[16] in VGPRs). Loads per step: one float2{delta,u} per lane
// (coalesced) + wave-uniform B/C float4s (L1 broadcast). No shuffles.
// Wave org: 2048 waves/pass = B_SZ*NC*(DI/64); block = 4 waves = 256 d.
//   blk: dg = blk&7 (d-group), bc = blk>>3, c = bc&31, b = bc>>5.
// ---------------------------------------------------------------------------
__global__ __launch_bounds__(256)
void scan_pass1(const float2* __restrict__ du, const float* __restrict__ xdbl,
                const float* __restrict__ Alog,
                float* __restrict__ Sb, float* __restrict__ SD)
{
    int tid = threadIdx.x, lane = tid & 63, wv = tid >> 6;
    int blk = blockIdx.x;
    int dg = blk & 7;
    int bc = blk >> 3;
    int c  = bc & (NC - 1);
    int b  = bc >> 5;
    int d  = (dg * 4 + wv) * 64 + lane;
    int base = c * LC;

    float ac2[NST];
#pragma unroll
    for (int q = 0; q < 4; q++) {
        float4 al = *(const float4*)(Alog + (size_t)d * NST + q * 4);
        ac2[q * 4 + 0] = -__expf(al.x) * LOG2E;
        ac2[q * 4 + 1] = -__expf(al.y) * LOG2E;
        ac2[q * 4 + 2] = -__expf(al.z) * LOG2E;
        ac2[q * 4 + 3] = -__expf(al.w) * LOG2E;
    }
    float h[NST];
#pragma unroll
    for (int n = 0; n < NST; n++) h[n] = 0.f;
    float sumD = 0.f;

    const float2* dup = du + (size_t)(b * SEQ + base) * DI + d;
    const float*  xr  = xdbl + (size_t)(b * SEQ + base) * XPD + RNK;

#pragma unroll 4
    for (int l = 0; l < LC; l++) {
        float2 duv = dup[(size_t)l * DI];
        float4 Bv[4];
#pragma unroll
        for (int q = 0; q < 4; q++) Bv[q] = *(const float4*)(xr + (size_t)l * XPD + q * 4);
        float dl  = duv.x;
        float dlu = dl * duv.y;
        sumD += dl;
#pragma unroll
        for (int n = 0; n < NST; n++) {
            float dA = EXP2F(dl * ac2[n]);
            h[n] = h[n] * dA + dlu * ((const float*)Bv)[n];
        }
    }

    size_t o = (size_t)c * NCH + ((size_t)b * DI + d) * NST;
#pragma unroll
    for (int q = 0; q < 4; q++)
        *(float4*)(Sb + o + q * 4) = make_float4(h[q*4], h[q*4+1], h[q*4+2], h[q*4+3]);
    SD[(size_t)c * (B_SZ * DI) + b * DI + d] = sumD;
}

// ---- combine: serial prefix over NC chunks; Sb <- h_init (in place).
// P recomputed as exp2(ac2 * sumDelta) -- avoids storing 16 P's per chain. ----
__global__ __launch_bounds__(256)
void scan_combine(float* __restrict__ Sb, const float* __restrict__ SD,
                  const float* __restrict__ Alog)
{
    int i = blockIdx.x * 256 + threadIdx.x;   // chain 0..NCH-1
    int n = i & 15;
    int d = (i >> 4) & (DI - 1);
    int b = i >> 15;
    float ac2 = -__expf(Alog[(size_t)d * NST + n]) * LOG2E;
    float h = 0.f;
#pragma unroll
    for (int c = 0; c < NC; c++) {
        float s = Sb[(size_t)c * NCH + i];
        float p = EXP2F(ac2 * SD[(size_t)c * (B_SZ * DI) + b * DI + d]);
        Sb[(size_t)c * NCH + i] = h;
        h = s + p * h;
    }
}

// ---- pass 2: rerun chunk from exact h_init; y = (scan + u*Dp) * zs -> bf16 ----
__global__ __launch_bounds__(256)
void scan_pass2(const float2* __restrict__ du, const float* __restrict__ xdbl,
                const float* __restrict__ zs, const float* __restrict__ Alog,
                const float* __restrict__ Dp, const float* __restrict__ Hinit,
                ushort_t* __restrict__ ybf)
{
    int tid = threadIdx.x, lane = tid & 63, wv = tid >> 6;
    int blk = blockIdx.x;
    int dg = blk & 7;
    int bc = blk >> 3;
    int c  = bc & (NC - 1);
    int b  = bc >> 5;
    int d  = (dg * 4 + wv) * 64 + lane;
    int base = c * LC;

    float ac2[NST];
#pragma unroll
    for (int q = 0; q < 4; q++) {
        float4 al = *(const float4*)(Alog + (size_t)d * NST + q * 4);
        ac2[q * 4 + 0] = -__expf(al.x) * LOG2E;
        ac2[q * 4 + 1] = -__expf(al.y) * LOG2E;
        ac2[q * 4 + 2] = -__expf(al.z) * LOG2E;
        ac2[q * 4 + 3] = -__expf(al.w) * LOG2E;
    }
    float dp = Dp[d];
    float h[NST];
    {
        size_t o = (size_t)c * NCH + ((size_t)b * DI + d) * NST;
#pragma unroll
        for (int q = 0; q < 4; q++) {
            float4 hv = *(const float4*)(Hinit + o + q * 4);
            h[q*4] = hv.x; h[q*4+1] = hv.y; h[q*4+2] = hv.z; h[q*4+3] = hv.w;
        }
    }

    const float2* dup = du + (size_t)(b * SEQ + base) * DI + d;
    const float*  xr  = xdbl + (size_t)(b * SEQ + base) * XPD + RNK;
    const float*  zp  = zs + (size_t)(b * SEQ + base) * DI + d;
    ushort_t*     yp  = ybf + (size_t)(b * SEQ + base) * DI + d;

#pragma unroll 4
    for (int l = 0; l < LC; l++) {
        float2 duv = dup[(size_t)l * DI];
        float4 Bv[4], Cv[4];
#pragma unroll
        for (int q = 0; q < 4; q++) {
            Bv[q] = *(const float4*)(xr + (size_t)l * XPD + q * 4);
            Cv[q] = *(const float4*)(xr + (size_t)l * XPD + NST + q * 4);
        }
        float dl  = duv.x;
        float dlu = dl * duv.y;
        float y = 0.f;
#pragma unroll
        for (int n = 0; n < NST; n++) {
            float dA = EXP2F(dl * ac2[n]);
            h[n] = h[n] * dA + dlu * ((const float*)Bv)[n];
            y += h[n] * ((const float*)Cv)[n];
        }
        float yv = (y + duv.y * dp) * zp[(size_t)l * DI];
        yp[(size_t)l * DI] = f2bf(yv);
    }
}

// ---------------------------------------------------------------------------
extern "C" void kernel_launch(void* const* d_in, const int* in_sizes, int n_in,
                              void* d_out, int out_size, void* d_ws, size_t ws_size,
                              hipStream_t stream)
{
    const float* x = (const float*)d_in[0];
    float* wsf = (float*)d_ws;

    // fp32 region (element counts in floats)
    float*  xz  = wsf;                               // 8388608
    float2* du  = (float2*)(xz + (size_t)M_TOT * 2 * DI);  // 4194304 float2 = 8388608 f
    float*  zs  = (float*)(du + (size_t)M_TOT * DI);       // 4194304
    float*  xdbl = zs + (size_t)M_TOT * DI;                // 196608
    // bf16 region
    ushort_t* xbf    = (ushort_t*)(xdbl + (size_t)M_TOT * XPD);
    ushort_t* ubf    = xbf   + (size_t)M_TOT * DM;       // 4194304
    ushort_t* ybf    = ubf   + (size_t)M_TOT * DI;       // 4194304
    ushort_t* inWbf  = ybf   + (size_t)M_TOT * DI;       // 4194304 ush = 8.39 MB
    ushort_t* xpWbf  = inWbf + (size_t)2 * DI * DM;      // 196608
    ushort_t* outWbf = xpWbf + (size_t)XPD * DI;         // 2097152

    // Scan scratch overlays (consumed before the overlain buffer is reused;
    // xbf and inWbf are reconverted at the top of every direction):
    //   Sb (NC*NCH floats = 8.39 MB) on inWbf (8.39 MB)
    //   SD (NC*B_SZ*DI floats = 0.5 MB) on xbf (4.2 MB)
    float* Sb = (float*)inWbf;
    float* SD = (float*)xbf;

    float* out = (float*)d_out;
    dim3 blk(256);

    for (int dir = 0; dir < 2; dir++) {
        int pb = 1 + dir * 9;
        const float* inW   = (const float*)d_in[pb + 0];
        const float* convW = (const float*)d_in[pb + 1];
        const float* convB = (const float*)d_in[pb + 2];
        const float* xpW   = (const float*)d_in[pb + 3];
        const float* dtW   = (const float*)d_in[pb + 4];
        const float* dtB   = (const float*)d_in[pb + 5];
        const float* Alog  = (const float*)d_in[pb + 6];
        const float* Dp    = (const float*)d_in[pb + 7];
        const float* outW  = (const float*)d_in[pb + 8];

        // conversions (xbf/inWbf reconverted each dir: their space doubles as
        // scan scratch after GEMM1 consumed them)
        f32_to_bf16<<<(M_TOT * DM) / 1024, blk, 0, stream>>>(x, xbf);
        f32_to_bf16<<<(2 * DI * DM) / 1024, blk, 0, stream>>>(inW, inWbf);
        f32_to_bf16<<<(XPD * DI) / 1024, blk, 0, stream>>>(xpW, xpWbf);
        f32_to_bf16<<<(DM * DI) / 1024, blk, 0, stream>>>(outW, outWbf);

        // xz = X(dir) * inW^T   [2048 x 4096], K=1024
        gemm_mfma<128, 128><<<dim3((2 * DI) / 128, M_TOT / 128), blk, 0, stream>>>(
            xbf, inWbf, xz, M_TOT, 2 * DI, DM, dir, 0, 1.f, 0);

        // u = silu(conv(xi)+convB) -> du.y, ubf ; zs = silu(z)
        conv_silu<<<(M_TOT * DI / 4) / 256, blk, 0, stream>>>(xz, convW, convB,
                                                              (float*)du, ubf, zs);

        // xdbl = u * xpW^T   [2048 x 96], K=2048
        gemm_mfma<64, 64><<<dim3((XPD + 63) / 64, M_TOT / 64), blk, 0, stream>>>(
            ubf, xpWbf, xdbl, M_TOT, XPD, DI, 0, 0, 1.f, 0);

        // delta -> du.x
        delta_gemm<<<dim3(DI / 64, M_TOT / 64), blk, 0, stream>>>(xdbl, dtW, dtB,
                                                                  (float*)du);

        // chunked exact scan (lane=d, 16 states/lane)
        scan_pass1<<<B_SZ * NC * 8, blk, 0, stream>>>(du, xdbl, Alog, Sb, SD);
        scan_combine<<<NCH / 256, blk, 0, stream>>>(Sb, SD, Alog);
        scan_pass2<<<B_SZ * NC * 8, blk, 0, stream>>>(du, xdbl, zs, Alog, Dp, Sb, ybf);

        // out (+)= 0.5 * y * outW^T
        gemm_mfma<128, 128><<<dim3(DM / 128, M_TOT / 128), blk, 0, stream>>>(
            ybf, outWbf, out, M_TOT, DM, DI, 0, dir, 0.5f, dir);
    }
}

// Round 6
// 492.158 us; speedup vs baseline: 1.5089x; 1.5089x over previous
//
#include <hip/hip_runtime.h>
#include <math.h>

#define B_SZ 2
#define SEQ  1024
#define DM   1024
#define DI   2048
#define NST  16
#define RNK  64
#define XPD  96            // RNK + 2*NST
#define M_TOT (B_SZ*SEQ)   // 2048
#define NC   32            // scan chunks
#define LC   (SEQ/NC)      // 32 steps per chunk
#define NCH  65536         // total chains = B_SZ*DI*NST

typedef unsigned short ushort_t;
typedef __attribute__((ext_vector_type(8))) short short8;   // 8 bf16 = 4 VGPRs
typedef __attribute__((ext_vector_type(4))) float f32x4;

#if __has_builtin(__builtin_amdgcn_exp2f)
#define EXP2F __builtin_amdgcn_exp2f
#else
#define EXP2F exp2f
#endif
#define LOG2E 1.44269504f

__device__ __forceinline__ ushort_t f2bf(float f) {
    unsigned u = __float_as_uint(f);
    u += 0x7fff + ((u >> 16) & 1);           // round-to-nearest-even
    return (ushort_t)(u >> 16);
}
__device__ __forceinline__ float bf2f(ushort_t v) {
    return __uint_as_float(((unsigned)v) << 16);
}

// ---------------------------------------------------------------------------
// fp32 -> bf16 bulk convert (n multiple of 1024; float4 per thread)
// ---------------------------------------------------------------------------
__global__ __launch_bounds__(256)
void f32_to_bf16(const float* __restrict__ in, ushort_t* __restrict__ out)
{
    int i = blockIdx.x * 256 + threadIdx.x;
    float4 v = ((const float4*)in)[i];
    ushort4 o;
    o.x = f2bf(v.x); o.y = f2bf(v.y); o.z = f2bf(v.z); o.w = f2bf(v.w);
    ((ushort4*)out)[i] = o;
}

// strided variant: in [rows x rowLen] contiguous -> out rows with stride outLd
__global__ __launch_bounds__(256)
void f32_to_bf16_stride(const float* __restrict__ in, ushort_t* __restrict__ out,
                        int rowLen4, int outLd)
{
    int i = blockIdx.x * 256 + threadIdx.x;      // one float4 per thread
    int row = i / rowLen4;
    int c4  = (i - row * rowLen4) << 2;
    float4 v = ((const float4*)in)[i];
    ushort4 o;
    o.x = f2bf(v.x); o.y = f2bf(v.y); o.z = f2bf(v.z); o.w = f2bf(v.w);
    *(ushort4*)(out + (size_t)row * outLd + c4) = o;
}

// ---------------------------------------------------------------------------
// m97-style bf16 MFMA NT GEMM, 128x128 tile, BK=64, direct global->LDS
// staging (global_load_lds width 16) with XOR-swizzled unpadded LDS.
// D[M,N] = A[M,K'] (rows kStart..) * W[N,K']^T over kLen; split via blockIdx.z.
// LDS layout: tile[r][c16] at byte r*128 + (c16 ^ (r&7))*16  (c16 = 16B chunk).
// OUT_BF16: D is bf16 [M x ldD]; else fp32 partials D + z*M*ldD.
// ---------------------------------------------------------------------------
__device__ __forceinline__ void load_lds16(const ushort_t* g, ushort_t* l) {
    __builtin_amdgcn_global_load_lds(
        (const __attribute__((address_space(1))) void*)g,
        (__attribute__((address_space(3))) void*)l, 16, 0, 0);
}

template<bool OUT_BF16>
__global__ __launch_bounds__(256)
void gemm_gll(const ushort_t* __restrict__ A, const ushort_t* __restrict__ W,
              void* __restrict__ D, int M, int N, int K, int kLen, int ldD)
{
    __shared__ __align__(16) ushort_t As[128 * 64];
    __shared__ __align__(16) ushort_t Ws[128 * 64];
    const int t    = threadIdx.x;
    const int lane = t & 63;
    const int wave = t >> 6;
    const int wr   = (wave >> 1) * 64;
    const int wc   = (wave & 1) * 64;

    const int m0 = blockIdx.y * 128;
    const int n0 = blockIdx.x * 128;
    const int kStart = blockIdx.z * kLen;

    const int srow   = lane >> 3;                      // 0..7 within 8-row group
    const int gchunk = (lane & 7) ^ srow;              // swizzled source chunk

    f32x4 acc[4][4] = {};

    for (int k0 = kStart; k0 < kStart + kLen; k0 += 64) {
#pragma unroll
        for (int it = 0; it < 4; it++) {
            const int rb = wave * 32 + it * 8;
            load_lds16(A + (size_t)(m0 + rb + srow) * K + k0 + gchunk * 8,
                       As + rb * 64);
            load_lds16(W + (size_t)(n0 + rb + srow) * K + k0 + gchunk * 8,
                       Ws + rb * 64);
        }
        __syncthreads();   // vmcnt(0) drain + barrier: LDS tiles ready
#pragma unroll
        for (int kk = 0; kk < 2; kk++) {
            const int kc = kk * 4 + (lane >> 4);       // logical 16B chunk
            short8 af[4], bf[4];
#pragma unroll
            for (int i = 0; i < 4; i++) {
                int r = wr + i * 16 + (lane & 15);
                af[i] = *(const short8*)(As + r * 64 + ((kc ^ (r & 7)) << 3));
            }
#pragma unroll
            for (int j = 0; j < 4; j++) {
                int r = wc + j * 16 + (lane & 15);
                bf[j] = *(const short8*)(Ws + r * 64 + ((kc ^ (r & 7)) << 3));
            }
#pragma unroll
            for (int i = 0; i < 4; i++)
#pragma unroll
                for (int j = 0; j < 4; j++)
                    acc[i][j] = __builtin_amdgcn_mfma_f32_16x16x32_bf16(
                        af[i], bf[j], acc[i][j], 0, 0, 0);
        }
        __syncthreads();   // readers done before next stage overwrites
    }

    if (OUT_BF16) {
        ushort_t* Dp = (ushort_t*)D;
#pragma unroll
        for (int i = 0; i < 4; i++)
#pragma unroll
            for (int r = 0; r < 4; r++) {
                int m = m0 + wr + i * 16 + ((lane >> 4) << 2) + r;
#pragma unroll
                for (int j = 0; j < 4; j++) {
                    int n = n0 + wc + j * 16 + (lane & 15);
                    Dp[(size_t)m * ldD + n] = f2bf(acc[i][j][r]);
                }
            }
    } else {
        float* Dp = (float*)D + (size_t)blockIdx.z * M * ldD;
#pragma unroll
        for (int i = 0; i < 4; i++)
#pragma unroll
            for (int r = 0; r < 4; r++) {
                int m = m0 + wr + i * 16 + ((lane >> 4) << 2) + r;
#pragma unroll
                for (int j = 0; j < 4; j++) {
                    int n = n0 + wc + j * 16 + (lane & 15);
                    Dp[(size_t)m * ldD + n] = acc[i][j][r];
                }
            }
    }
}

// out = 0.5 * (P0 + P1 + P2 + P3)
__global__ __launch_bounds__(256)
void reduce4(const float* __restrict__ P, float* __restrict__ out)
{
    int i = blockIdx.x * 256 + threadIdx.x;
    const size_t S = (size_t)M_TOT * DM / 4;
    float4 a = ((const float4*)P)[i];
    float4 b = ((const float4*)P)[i + S];
    float4 c = ((const float4*)P)[i + 2 * S];
    float4 d = ((const float4*)P)[i + 3 * S];
    float4 o;
    o.x = 0.5f * (a.x + b.x + c.x + d.x);
    o.y = 0.5f * (a.y + b.y + c.y + d.y);
    o.z = 0.5f * (a.z + b.z + c.z + d.z);
    o.w = 0.5f * (a.w + b.w + c.w + d.w);
    ((float4*)out)[i] = o;
}

// ---------------------------------------------------------------------------
// Old padded-LDS MFMA GEMM (64x64), kept for GEMM2 (N=96, needs masking).
// D = A[M,K] * W[N,K]^T, fp32 out.
// ---------------------------------------------------------------------------
#define LDSP 72

__global__ __launch_bounds__(256)
void gemm_mfma64(const ushort_t* __restrict__ A, const ushort_t* __restrict__ W,
                 float* __restrict__ D, int M, int N, int K)
{
    __shared__ __align__(16) ushort_t As[64 * LDSP];
    __shared__ __align__(16) ushort_t Ws[64 * LDSP];
    const int t    = threadIdx.x;
    const int lane = t & 63;
    const int wave = t >> 6;
    const int wr   = (wave >> 1) * 32;
    const int wc   = (wave & 1) * 32;

    f32x4 acc[2][2] = {};

    const int m0 = blockIdx.y * 64;
    const int n0 = blockIdx.x * 64;
    const int srow = t >> 3;
    const int scol = (t & 7) << 3;

    for (int k0 = 0; k0 < K; k0 += 64) {
        {
            int r = srow;   // 0..31
            short8 v = *(const short8*)(A + (size_t)(m0 + r) * K + k0 + scol);
            *(short8*)(&As[r * LDSP + scol]) = v;
            int r2 = 32 + srow;
            short8 v2 = *(const short8*)(A + (size_t)(m0 + r2) * K + k0 + scol);
            *(short8*)(&As[r2 * LDSP + scol]) = v2;
            int wn = n0 + r;
            short8 wv = {};
            if (wn < N) wv = *(const short8*)(W + (size_t)wn * K + k0 + scol);
            *(short8*)(&Ws[r * LDSP + scol]) = wv;
            int wn2 = n0 + r2;
            short8 wv2 = {};
            if (wn2 < N) wv2 = *(const short8*)(W + (size_t)wn2 * K + k0 + scol);
            *(short8*)(&Ws[r2 * LDSP + scol]) = wv2;
        }
        __syncthreads();
#pragma unroll
        for (int kk = 0; kk < 2; kk++) {
            const int kcol = kk * 32 + ((lane >> 4) << 3);
            short8 af[2], bfr[2];
#pragma unroll
            for (int i = 0; i < 2; i++)
                af[i] = *(const short8*)(&As[(wr + i * 16 + (lane & 15)) * LDSP + kcol]);
#pragma unroll
            for (int j = 0; j < 2; j++)
                bfr[j] = *(const short8*)(&Ws[(wc + j * 16 + (lane & 15)) * LDSP + kcol]);
#pragma unroll
            for (int i = 0; i < 2; i++)
#pragma unroll
                for (int j = 0; j < 2; j++)
                    acc[i][j] = __builtin_amdgcn_mfma_f32_16x16x32_bf16(
                        af[i], bfr[j], acc[i][j], 0, 0, 0);
        }
        __syncthreads();
    }

#pragma unroll
    for (int i = 0; i < 2; i++)
#pragma unroll
        for (int r = 0; r < 4; r++) {
            int m = m0 + wr + i * 16 + ((lane >> 4) << 2) + r;
#pragma unroll
            for (int j = 0; j < 2; j++) {
                int n = n0 + wc + j * 16 + (lane & 15);
                if (n < N) D[(size_t)m * N + n] = acc[i][j][r];
            }
        }
}

// ---------------------------------------------------------------------------
// delta = softplus(dt[M,64] * dtW[DI,64]^T + dtB) -> du[m][n].x
// ---------------------------------------------------------------------------
__global__ __launch_bounds__(256)
void delta_gemm(const float* __restrict__ xdbl, const float* __restrict__ dtW,
                const float* __restrict__ dtB, float* __restrict__ duf)
{
    __shared__ __align__(16) ushort_t As[64 * LDSP];
    __shared__ __align__(16) ushort_t Ws[64 * LDSP];
    const int t    = threadIdx.x;
    const int lane = t & 63;
    const int wave = t >> 6;
    const int wr   = (wave >> 1) * 32;
    const int wc   = (wave & 1) * 32;

    const int m0 = blockIdx.y * 64;
    const int n0 = blockIdx.x * 64;
    const int srow = t >> 2;            // 0..63
    const int scol = (t & 3) << 4;      // 0,16,32,48

    {
        const float* ap = xdbl + (size_t)(m0 + srow) * XPD + scol;
        const float* wp = dtW  + (size_t)(n0 + srow) * RNK + scol;
        float4 a[4], w[4];
#pragma unroll
        for (int q = 0; q < 4; q++) { a[q] = ((const float4*)ap)[q]; w[q] = ((const float4*)wp)[q]; }
        ushort_t* as  = &As[srow * LDSP + scol];
        ushort_t* wsp = &Ws[srow * LDSP + scol];
#pragma unroll
        for (int q = 0; q < 16; q++) {
            as[q]  = f2bf(((const float*)a)[q]);
            wsp[q] = f2bf(((const float*)w)[q]);
        }
    }
    __syncthreads();

    f32x4 acc[2][2] = {};
#pragma unroll
    for (int kk = 0; kk < 2; kk++) {
        const int kcol = kk * 32 + ((lane >> 4) << 3);
        short8 af[2], bfr[2];
#pragma unroll
        for (int i = 0; i < 2; i++)
            af[i] = *(const short8*)(&As[(wr + i * 16 + (lane & 15)) * LDSP + kcol]);
#pragma unroll
        for (int j = 0; j < 2; j++)
            bfr[j] = *(const short8*)(&Ws[(wc + j * 16 + (lane & 15)) * LDSP + kcol]);
#pragma unroll
        for (int i = 0; i < 2; i++)
#pragma unroll
            for (int j = 0; j < 2; j++)
                acc[i][j] = __builtin_amdgcn_mfma_f32_16x16x32_bf16(
                    af[i], bfr[j], acc[i][j], 0, 0, 0);
    }

#pragma unroll
    for (int j = 0; j < 2; j++) {
        int n = n0 + wc + j * 16 + (lane & 15);
        float bn = dtB[n];
#pragma unroll
        for (int i = 0; i < 2; i++) {
#pragma unroll
            for (int r = 0; r < 4; r++) {
                int m = m0 + wr + i * 16 + ((lane >> 4) << 2) + r;
                float v = acc[i][j][r] + bn;
                float sp = (v > 20.f) ? v : log1pf(__expf(v));
                duf[((size_t)m * DI + n) * 2] = sp;   // du.x
            }
        }
    }
}

// ---------------------------------------------------------------------------
// Depthwise conv(4) + bias + SiLU from bf16 xzall. dir=0: causal (l-3+j);
// dir=1: anti-causal (l+3-j) == causal conv on the flipped sequence, kept in
// natural order. Writes du.y (fp32) + ubf (bf16).
// ---------------------------------------------------------------------------
__global__ __launch_bounds__(256)
void conv_silu(const ushort_t* __restrict__ xzall, const float* __restrict__ convW,
               const float* __restrict__ convB, float* __restrict__ duf,
               ushort_t* __restrict__ ubf, int dir)
{
    int idx = blockIdx.x * 256 + threadIdx.x;   // over M_TOT*DI/4
    int di  = (idx & (DI / 4 - 1)) << 2;
    int m   = idx >> 9;
    int b   = m >> 10, l = m & (SEQ - 1);
    const ushort_t* xb = xzall + (size_t)b * SEQ * (4 * DI) + dir * (2 * DI) + di;

    float wv[4][4];
#pragma unroll
    for (int c = 0; c < 4; c++) {
        float4 w = *(const float4*)(convW + (di + c) * 4);
        wv[c][0] = w.x; wv[c][1] = w.y; wv[c][2] = w.z; wv[c][3] = w.w;
    }
    float4 cb = *(const float4*)(convB + di);
    float acc[4] = {cb.x, cb.y, cb.z, cb.w};
#pragma unroll
    for (int j = 0; j < 4; j++) {
        int srcl = dir ? (l + 3 - j) : (l - 3 + j);
        if ((unsigned)srcl < SEQ) {
            ushort4 xv = *(const ushort4*)(xb + (size_t)srcl * (4 * DI));
            acc[0] += wv[0][j] * bf2f(xv.x);
            acc[1] += wv[1][j] * bf2f(xv.y);
            acc[2] += wv[2][j] * bf2f(xv.z);
            acc[3] += wv[3][j] * bf2f(xv.w);
        }
    }
    size_t base = (size_t)m * DI + di;
    ushort4 o;
    float s0 = acc[0] / (1.f + __expf(-acc[0]));
    float s1 = acc[1] / (1.f + __expf(-acc[1]));
    float s2 = acc[2] / (1.f + __expf(-acc[2]));
    float s3 = acc[3] / (1.f + __expf(-acc[3]));
    duf[(base + 0) * 2 + 1] = s0;
    duf[(base + 1) * 2 + 1] = s1;
    duf[(base + 2) * 2 + 1] = s2;
    duf[(base + 3) * 2 + 1] = s3;
    o.x = f2bf(s0); o.y = f2bf(s1); o.z = f2bf(s2); o.w = f2bf(s3);
    *(ushort4*)(ubf + base) = o;
}

// ---------------------------------------------------------------------------
// Chunked selective scan (lane = d, 16 states/lane in VGPRs). dir=1 runs
// time-reversed (natural storage order). Logical step s -> row t.
// ---------------------------------------------------------------------------
__global__ __launch_bounds__(256)
void scan_pass1(const float2* __restrict__ du, const float* __restrict__ xdbl,
                const float* __restrict__ Alog,
                float* __restrict__ Sb, float* __restrict__ SD, int dir)
{
    int tid = threadIdx.x, lane = tid & 63, wv = tid >> 6;
    int blk = blockIdx.x;
    int dg = blk & 7;
    int bc = blk >> 3;
    int c  = bc & (NC - 1);
    int b  = bc >> 5;
    int d  = (dg * 4 + wv) * 64 + lane;
    int t0 = dir ? (SEQ - 1 - c * LC) : (c * LC);
    int rs = dir ? -1 : 1;

    float ac2[NST];
#pragma unroll
    for (int q = 0; q < 4; q++) {
        float4 al = *(const float4*)(Alog + (size_t)d * NST + q * 4);
        ac2[q * 4 + 0] = -__expf(al.x) * LOG2E;
        ac2[q * 4 + 1] = -__expf(al.y) * LOG2E;
        ac2[q * 4 + 2] = -__expf(al.z) * LOG2E;
        ac2[q * 4 + 3] = -__expf(al.w) * LOG2E;
    }
    float h[NST];
#pragma unroll
    for (int n = 0; n < NST; n++) h[n] = 0.f;
    float sumD = 0.f;

#pragma unroll 4
    for (int l = 0; l < LC; l++) {
        int t = t0 + rs * l;
        float2 duv = du[((size_t)b * SEQ + t) * DI + d];
        const float* xr = xdbl + ((size_t)b * SEQ + t) * XPD + RNK;
        float4 Bv[4];
#pragma unroll
        for (int q = 0; q < 4; q++) Bv[q] = *(const float4*)(xr + q * 4);
        float dl  = duv.x;
        float dlu = dl * duv.y;
        sumD += dl;
#pragma unroll
        for (int n = 0; n < NST; n++) {
            float dA = EXP2F(dl * ac2[n]);
            h[n] = h[n] * dA + dlu * ((const float*)Bv)[n];
        }
    }

    size_t o = (size_t)c * NCH + ((size_t)b * DI + d) * NST;
#pragma unroll
    for (int q = 0; q < 4; q++)
        *(float4*)(Sb + o + q * 4) = make_float4(h[q*4], h[q*4+1], h[q*4+2], h[q*4+3]);
    SD[(size_t)c * (B_SZ * DI) + b * DI + d] = sumD;
}

__global__ __launch_bounds__(256)
void scan_combine(float* __restrict__ Sb, const float* __restrict__ SD,
                  const float* __restrict__ Alog)
{
    int i = blockIdx.x * 256 + threadIdx.x;   // chain 0..NCH-1
    int n = i & 15;
    int d = (i >> 4) & (DI - 1);
    int b = i >> 15;
    float ac2 = -__expf(Alog[(size_t)d * NST + n]) * LOG2E;
    float h = 0.f;
#pragma unroll
    for (int c = 0; c < NC; c++) {
        float s = Sb[(size_t)c * NCH + i];
        float p = EXP2F(ac2 * SD[(size_t)c * (B_SZ * DI) + b * DI + d]);
        Sb[(size_t)c * NCH + i] = h;
        h = s + p * h;
    }
}

__global__ __launch_bounds__(256)
void scan_pass2(const float2* __restrict__ du, const float* __restrict__ xdbl,
                const ushort_t* __restrict__ xzall, const float* __restrict__ Alog,
                const float* __restrict__ Dp, const float* __restrict__ Hinit,
                ushort_t* __restrict__ ybf, int dir)
{
    int tid = threadIdx.x, lane = tid & 63, wv = tid >> 6;
    int blk = blockIdx.x;
    int dg = blk & 7;
    int bc = blk >> 3;
    int c  = bc & (NC - 1);
    int b  = bc >> 5;
    int d  = (dg * 4 + wv) * 64 + lane;
    int t0 = dir ? (SEQ - 1 - c * LC) : (c * LC);
    int rs = dir ? -1 : 1;

    float ac2[NST];
#pragma unroll
    for (int q = 0; q < 4; q++) {
        float4 al = *(const float4*)(Alog + (size_t)d * NST + q * 4);
        ac2[q * 4 + 0] = -__expf(al.x) * LOG2E;
        ac2[q * 4 + 1] = -__expf(al.y) * LOG2E;
        ac2[q * 4 + 2] = -__expf(al.z) * LOG2E;
        ac2[q * 4 + 3] = -__expf(al.w) * LOG2E;
    }
    float dp = Dp[d];
    float h[NST];
    {
        size_t o = (size_t)c * NCH + ((size_t)b * DI + d) * NST;
#pragma unroll
        for (int q = 0; q < 4; q++) {
            float4 hv = *(const float4*)(Hinit + o + q * 4);
            h[q*4] = hv.x; h[q*4+1] = hv.y; h[q*4+2] = hv.z; h[q*4+3] = hv.w;
        }
    }

#pragma unroll 4
    for (int l = 0; l < LC; l++) {
        int t = t0 + rs * l;
        size_t row = (size_t)b * SEQ + t;
        float2 duv = du[row * DI + d];
        const float* xr = xdbl + row * XPD + RNK;
        float4 Bv[4], Cv[4];
#pragma unroll
        for (int q = 0; q < 4; q++) {
            Bv[q] = *(const float4*)(xr + q * 4);
            Cv[q] = *(const float4*)(xr + NST + q * 4);
        }
        float dl  = duv.x;
        float dlu = dl * duv.y;
        float y = 0.f;
#pragma unroll
        for (int n = 0; n < NST; n++) {
            float dA = EXP2F(dl * ac2[n]);
            h[n] = h[n] * dA + dlu * ((const float*)Bv)[n];
            y += h[n] * ((const float*)Cv)[n];
        }
        float z = bf2f(xzall[row * (4 * DI) + dir * (2 * DI) + DI + d]);
        float yv = (y + duv.y * dp) * (z / (1.f + __expf(-z)));
        ybf[row * (2 * DI) + dir * DI + d] = f2bf(yv);
    }
}

// ---------------------------------------------------------------------------
extern "C" void kernel_launch(void* const* d_in, const int* in_sizes, int n_in,
                              void* d_out, int out_size, void* d_ws, size_t ws_size,
                              hipStream_t stream)
{
    const float* x = (const float*)d_in[0];
    char* wsb = (char*)d_ws;

    // layout (bytes), total 113.2 MB:
    ushort_t* xzall  = (ushort_t*)wsb;                       // 33,554,432  [M x 8192] bf16
    float2*   du     = (float2*)(wsb + 33554432);            // 33,554,432  (GEMM4 partials overlay)
    char*     xbfreg = wsb + 67108864;                       //  4,194,304
    ushort_t* ybf    = (ushort_t*)(wsb + 71303168);          // 16,777,216  [M x 2*DI] bf16
    ushort_t* inWcat = (ushort_t*)(wsb + 88080384);          // 16,777,216  (Sb+ubf overlay)
    ushort_t* outWcat= (ushort_t*)(wsb + 104857600);         //  8,388,608  [DM x 2*DI] bf16

    ushort_t* xbf   = (ushort_t*)xbfreg;                     // GEMM1 A (dead after GEMM1)
    float*    xdbl  = (float*)xbfreg;                        // overlay: [M x XPD] fp32 (3,145,728)
    ushort_t* xpWbf = (ushort_t*)(xbfreg + 3145728);         // 393,216
    float*    SD    = (float*)(xbfreg + 3538944);            // 524,288
    float*    Sb    = (float*)inWcat;                        // 8,388,608 (overlay after GEMM1)
    ushort_t* ubf   = inWcat + 4194304;                      // 8,388,608 bf16 (second half)
    float*    part  = (float*)du;                            // GEMM4 partials (after scans)

    float* out = (float*)d_out;
    dim3 blk(256);

    // --- prologue: conversions + merged GEMM1 ---
    f32_to_bf16<<<(M_TOT * DM) / 1024, blk, 0, stream>>>(x, xbf);
    f32_to_bf16<<<(2 * DI * DM) / 1024, blk, 0, stream>>>((const float*)d_in[1], inWcat);
    f32_to_bf16<<<(2 * DI * DM) / 1024, blk, 0, stream>>>((const float*)d_in[10],
                                                          inWcat + (size_t)2 * DI * DM);
    f32_to_bf16_stride<<<(DM * DI) / 1024, blk, 0, stream>>>(
        (const float*)d_in[9], outWcat, DI / 4, 2 * DI);
    f32_to_bf16_stride<<<(DM * DI) / 1024, blk, 0, stream>>>(
        (const float*)d_in[18], outWcat + DI, DI / 4, 2 * DI);

    // xzall = x * [inW_f; inW_b]^T   [2048 x 8192], K=1024, bf16 out
    gemm_gll<true><<<dim3(8192 / 128, M_TOT / 128, 1), blk, 0, stream>>>(
        xbf, inWcat, xzall, M_TOT, 8192, DM, DM, 8192);

    for (int dir = 0; dir < 2; dir++) {
        int pb = 1 + dir * 9;
        const float* convW = (const float*)d_in[pb + 1];
        const float* convB = (const float*)d_in[pb + 2];
        const float* xpW   = (const float*)d_in[pb + 3];
        const float* dtW   = (const float*)d_in[pb + 4];
        const float* dtB   = (const float*)d_in[pb + 5];
        const float* Alog  = (const float*)d_in[pb + 6];
        const float* Dp    = (const float*)d_in[pb + 7];

        f32_to_bf16<<<(XPD * DI) / 1024, blk, 0, stream>>>(xpW, xpWbf);

        // u = silu(conv(xi)) -> du.y, ubf   (natural order, dir-dependent taps)
        conv_silu<<<(M_TOT * DI / 4) / 256, blk, 0, stream>>>(xzall, convW, convB,
                                                              (float*)du, ubf, dir);

        // xdbl = u * xpW^T   [2048 x 96], K=2048
        gemm_mfma64<<<dim3((XPD + 63) / 64, M_TOT / 64), blk, 0, stream>>>(
            ubf, xpWbf, xdbl, M_TOT, XPD, DI);

        // delta -> du.x
        delta_gemm<<<dim3(DI / 64, M_TOT / 64), blk, 0, stream>>>(xdbl, dtW, dtB,
                                                                  (float*)du);

        // chunked exact scan (time-reversed for dir=1)
        scan_pass1<<<B_SZ * NC * 8, blk, 0, stream>>>(du, xdbl, Alog, Sb, SD, dir);
        scan_combine<<<NCH / 256, blk, 0, stream>>>(Sb, SD, Alog);
        scan_pass2<<<B_SZ * NC * 8, blk, 0, stream>>>(du, xdbl, xzall, Alog, Dp,
                                                      Sb, ybf, dir);
    }

    // out = 0.5 * [y_f | y_b] * [outW_f | outW_b]^T : K=4096, splitK=4
    gemm_gll<false><<<dim3(DM / 128, M_TOT / 128, 4), blk, 0, stream>>>(
        ybf, outWcat, part, M_TOT, DM, 2 * DI, DI / 2, DM);
    reduce4<<<(M_TOT * DM / 4) / 256, blk, 0, stream>>>(part, out);
}

// Round 7
// 413.017 us; speedup vs baseline: 1.7981x; 1.1916x over previous
//
#include <hip/hip_runtime.h>
#include <math.h>

#define B_SZ 2
#define SEQ  1024
#define DM   1024
#define DI   2048
#define NST  16
#define RNK  64
#define XPD  96            // RNK + 2*NST
#define M_TOT (B_SZ*SEQ)   // 2048
#define NC   32            // scan chunks
#define LC   (SEQ/NC)      // 32 steps per chunk
#define NCH  65536         // total chains = B_SZ*DI*NST

typedef unsigned short ushort_t;
typedef __attribute__((ext_vector_type(8))) short short8;   // 8 bf16 = 4 VGPRs
typedef __attribute__((ext_vector_type(4))) float f32x4;

#if __has_builtin(__builtin_amdgcn_exp2f)
#define EXP2F __builtin_amdgcn_exp2f
#else
#define EXP2F exp2f
#endif
#define LOG2E 1.44269504f

__device__ __forceinline__ ushort_t f2bf(float f) {
    unsigned u = __float_as_uint(f);
    u += 0x7fff + ((u >> 16) & 1);           // round-to-nearest-even
    return (ushort_t)(u >> 16);
}
__device__ __forceinline__ float bf2f(ushort_t v) {
    return __uint_as_float(((unsigned)v) << 16);
}

// ---------------------------------------------------------------------------
// fp32 -> bf16 bulk convert (n multiple of 1024; float4 per thread)
// ---------------------------------------------------------------------------
__global__ __launch_bounds__(256)
void f32_to_bf16(const float* __restrict__ in, ushort_t* __restrict__ out)
{
    int i = blockIdx.x * 256 + threadIdx.x;
    float4 v = ((const float4*)in)[i];
    ushort4 o;
    o.x = f2bf(v.x); o.y = f2bf(v.y); o.z = f2bf(v.z); o.w = f2bf(v.w);
    ((ushort4*)out)[i] = o;
}

// ---------------------------------------------------------------------------
// One-shot prologue conversion: x, inW_f, inW_b (contig) + outW_f, outW_b
// (strided interleave into outWcat [DM x 2*DI]). Segmented by blockIdx.
// blocks: 2048 | 4096 | 4096 | 2048 | 2048  = 14336
// ---------------------------------------------------------------------------
__global__ __launch_bounds__(256)
void convert_all(const float* __restrict__ x,
                 const float* __restrict__ inWf, const float* __restrict__ inWb,
                 const float* __restrict__ outWf, const float* __restrict__ outWb,
                 ushort_t* __restrict__ xbf, ushort_t* __restrict__ inWcat,
                 ushort_t* __restrict__ outWcat)
{
    int bid = blockIdx.x;
    const float* src; ushort_t* dst; int rel; int strided = 0;
    if (bid < 2048)       { rel = bid;         src = x;     dst = xbf; }
    else if (bid < 6144)  { rel = bid - 2048;  src = inWf;  dst = inWcat; }
    else if (bid < 10240) { rel = bid - 6144;  src = inWb;  dst = inWcat + (size_t)2 * DI * DM; }
    else if (bid < 12288) { rel = bid - 10240; src = outWf; dst = outWcat;      strided = 1; }
    else                  { rel = bid - 12288; src = outWb; dst = outWcat + DI; strided = 1; }
    int i = rel * 256 + threadIdx.x;
    float4 v = ((const float4*)src)[i];
    ushort4 o;
    o.x = f2bf(v.x); o.y = f2bf(v.y); o.z = f2bf(v.z); o.w = f2bf(v.w);
    if (!strided) {
        ((ushort4*)dst)[i] = o;
    } else {
        int row = i >> 9;                 // rowLen4 = DI/4 = 512
        int c4  = (i - (row << 9)) << 2;
        *(ushort4*)(dst + (size_t)row * (2 * DI) + c4) = o;
    }
}

// ---------------------------------------------------------------------------
// m97-style bf16 MFMA NT GEMM, 128x128 tile, BK=64, direct global->LDS
// staging (global_load_lds width 16) with XOR-swizzled unpadded LDS.
// OUT_BF16: D bf16 [M x ldD]; else fp32 partials D + z*M*ldD.
// ---------------------------------------------------------------------------
__device__ __forceinline__ void load_lds16(const ushort_t* g, ushort_t* l) {
    __builtin_amdgcn_global_load_lds(
        (const __attribute__((address_space(1))) void*)g,
        (__attribute__((address_space(3))) void*)l, 16, 0, 0);
}

template<bool OUT_BF16>
__global__ __launch_bounds__(256)
void gemm_gll(const ushort_t* __restrict__ A, const ushort_t* __restrict__ W,
              void* __restrict__ D, int M, int N, int K, int kLen, int ldD)
{
    __shared__ __align__(16) ushort_t As[128 * 64];
    __shared__ __align__(16) ushort_t Ws[128 * 64];
    const int t    = threadIdx.x;
    const int lane = t & 63;
    const int wave = t >> 6;
    const int wr   = (wave >> 1) * 64;
    const int wc   = (wave & 1) * 64;

    const int m0 = blockIdx.y * 128;
    const int n0 = blockIdx.x * 128;
    const int kStart = blockIdx.z * kLen;

    const int srow   = lane >> 3;
    const int gchunk = (lane & 7) ^ srow;

    f32x4 acc[4][4] = {};

    for (int k0 = kStart; k0 < kStart + kLen; k0 += 64) {
#pragma unroll
        for (int it = 0; it < 4; it++) {
            const int rb = wave * 32 + it * 8;
            load_lds16(A + (size_t)(m0 + rb + srow) * K + k0 + gchunk * 8,
                       As + rb * 64);
            load_lds16(W + (size_t)(n0 + rb + srow) * K + k0 + gchunk * 8,
                       Ws + rb * 64);
        }
        __syncthreads();
#pragma unroll
        for (int kk = 0; kk < 2; kk++) {
            const int kc = kk * 4 + (lane >> 4);
            short8 af[4], bf[4];
#pragma unroll
            for (int i = 0; i < 4; i++) {
                int r = wr + i * 16 + (lane & 15);
                af[i] = *(const short8*)(As + r * 64 + ((kc ^ (r & 7)) << 3));
            }
#pragma unroll
            for (int j = 0; j < 4; j++) {
                int r = wc + j * 16 + (lane & 15);
                bf[j] = *(const short8*)(Ws + r * 64 + ((kc ^ (r & 7)) << 3));
            }
#pragma unroll
            for (int i = 0; i < 4; i++)
#pragma unroll
                for (int j = 0; j < 4; j++)
                    acc[i][j] = __builtin_amdgcn_mfma_f32_16x16x32_bf16(
                        af[i], bf[j], acc[i][j], 0, 0, 0);
        }
        __syncthreads();
    }

    if (OUT_BF16) {
        ushort_t* Dp = (ushort_t*)D;
#pragma unroll
        for (int i = 0; i < 4; i++)
#pragma unroll
            for (int r = 0; r < 4; r++) {
                int m = m0 + wr + i * 16 + ((lane >> 4) << 2) + r;
#pragma unroll
                for (int j = 0; j < 4; j++) {
                    int n = n0 + wc + j * 16 + (lane & 15);
                    Dp[(size_t)m * ldD + n] = f2bf(acc[i][j][r]);
                }
            }
    } else {
        float* Dp = (float*)D + (size_t)blockIdx.z * M * ldD;
#pragma unroll
        for (int i = 0; i < 4; i++)
#pragma unroll
            for (int r = 0; r < 4; r++) {
                int m = m0 + wr + i * 16 + ((lane >> 4) << 2) + r;
#pragma unroll
                for (int j = 0; j < 4; j++) {
                    int n = n0 + wc + j * 16 + (lane & 15);
                    Dp[(size_t)m * ldD + n] = acc[i][j][r];
                }
            }
    }
}

// out = 0.5 * (P0 + P1 + P2 + P3)
__global__ __launch_bounds__(256)
void reduce4(const float* __restrict__ P, float* __restrict__ out)
{
    int i = blockIdx.x * 256 + threadIdx.x;
    const size_t S = (size_t)M_TOT * DM / 4;
    float4 a = ((const float4*)P)[i];
    float4 b = ((const float4*)P)[i + S];
    float4 c = ((const float4*)P)[i + 2 * S];
    float4 d = ((const float4*)P)[i + 3 * S];
    float4 o;
    o.x = 0.5f * (a.x + b.x + c.x + d.x);
    o.y = 0.5f * (a.y + b.y + c.y + d.y);
    o.z = 0.5f * (a.z + b.z + c.z + d.z);
    o.w = 0.5f * (a.w + b.w + c.w + d.w);
    ((float4*)out)[i] = o;
}

// ---------------------------------------------------------------------------
// GEMM2 split-K: P[z] = A[M,Kc] * W[N,Kc]^T  (64x64 tile, N=96 masked)
// Partials [8 x M x XPD] fp32; grid (2, M/64, 8), kLen = K/8 = 256.
// ---------------------------------------------------------------------------
#define LDSP 72

__global__ __launch_bounds__(256)
void gemm2_splitk(const ushort_t* __restrict__ A, const ushort_t* __restrict__ W,
                  float* __restrict__ P, int M, int N, int K, int kLen)
{
    __shared__ __align__(16) ushort_t As[64 * LDSP];
    __shared__ __align__(16) ushort_t Ws[64 * LDSP];
    const int t    = threadIdx.x;
    const int lane = t & 63;
    const int wave = t >> 6;
    const int wr   = (wave >> 1) * 32;
    const int wc   = (wave & 1) * 32;

    f32x4 acc[2][2] = {};

    const int m0 = blockIdx.y * 64;
    const int n0 = blockIdx.x * 64;
    const int kStart = blockIdx.z * kLen;
    const int srow = t >> 3;
    const int scol = (t & 7) << 3;

    for (int k0 = kStart; k0 < kStart + kLen; k0 += 64) {
        {
            int r = srow;
            short8 v = *(const short8*)(A + (size_t)(m0 + r) * K + k0 + scol);
            *(short8*)(&As[r * LDSP + scol]) = v;
            int r2 = 32 + srow;
            short8 v2 = *(const short8*)(A + (size_t)(m0 + r2) * K + k0 + scol);
            *(short8*)(&As[r2 * LDSP + scol]) = v2;
            int wn = n0 + r;
            short8 wv = {};
            if (wn < N) wv = *(const short8*)(W + (size_t)wn * K + k0 + scol);
            *(short8*)(&Ws[r * LDSP + scol]) = wv;
            int wn2 = n0 + r2;
            short8 wv2 = {};
            if (wn2 < N) wv2 = *(const short8*)(W + (size_t)wn2 * K + k0 + scol);
            *(short8*)(&Ws[r2 * LDSP + scol]) = wv2;
        }
        __syncthreads();
#pragma unroll
        for (int kk = 0; kk < 2; kk++) {
            const int kcol = kk * 32 + ((lane >> 4) << 3);
            short8 af[2], bfr[2];
#pragma unroll
            for (int i = 0; i < 2; i++)
                af[i] = *(const short8*)(&As[(wr + i * 16 + (lane & 15)) * LDSP + kcol]);
#pragma unroll
            for (int j = 0; j < 2; j++)
                bfr[j] = *(const short8*)(&Ws[(wc + j * 16 + (lane & 15)) * LDSP + kcol]);
#pragma unroll
            for (int i = 0; i < 2; i++)
#pragma unroll
                for (int j = 0; j < 2; j++)
                    acc[i][j] = __builtin_amdgcn_mfma_f32_16x16x32_bf16(
                        af[i], bfr[j], acc[i][j], 0, 0, 0);
        }
        __syncthreads();
    }

    float* Pz = P + (size_t)blockIdx.z * M * XPD;
#pragma unroll
    for (int i = 0; i < 2; i++)
#pragma unroll
        for (int r = 0; r < 4; r++) {
            int m = m0 + wr + i * 16 + ((lane >> 4) << 2) + r;
#pragma unroll
            for (int j = 0; j < 2; j++) {
                int n = n0 + wc + j * 16 + (lane & 15);
                if (n < N) Pz[(size_t)m * XPD + n] = acc[i][j][r];
            }
        }
}

// xdbl = sum of 8 partials
__global__ __launch_bounds__(256)
void xdbl_reduce(const float* __restrict__ P, float* __restrict__ xdbl)
{
    int i = blockIdx.x * 256 + threadIdx.x;   // float4 over M*XPD/4
    const size_t S = (size_t)M_TOT * XPD / 4;
    float4 s = ((const float4*)P)[i];
#pragma unroll
    for (int z = 1; z < 8; z++) {
        float4 v = ((const float4*)P)[i + z * S];
        s.x += v.x; s.y += v.y; s.z += v.z; s.w += v.w;
    }
    ((float4*)xdbl)[i] = s;
}

// ---------------------------------------------------------------------------
// delta = softplus(dt[M,64] * dtW[DI,64]^T + dtB) -> delta[M x DI] fp32
// Single-K-tile MFMA GEMM; fp32->bf16 packed during LDS staging.
// ---------------------------------------------------------------------------
__global__ __launch_bounds__(256)
void delta_gemm(const float* __restrict__ xdbl, const float* __restrict__ dtW,
                const float* __restrict__ dtB, float* __restrict__ delta)
{
    __shared__ __align__(16) ushort_t As[64 * LDSP];
    __shared__ __align__(16) ushort_t Ws[64 * LDSP];
    const int t    = threadIdx.x;
    const int lane = t & 63;
    const int wave = t >> 6;
    const int wr   = (wave >> 1) * 32;
    const int wc   = (wave & 1) * 32;

    const int m0 = blockIdx.y * 64;
    const int n0 = blockIdx.x * 64;
    const int srow = t >> 2;            // 0..63
    const int scol = (t & 3) << 4;      // 0,16,32,48

    {
        const float* ap = xdbl + (size_t)(m0 + srow) * XPD + scol;
        const float* wp = dtW  + (size_t)(n0 + srow) * RNK + scol;
        float4 a[4], w[4];
#pragma unroll
        for (int q = 0; q < 4; q++) { a[q] = ((const float4*)ap)[q]; w[q] = ((const float4*)wp)[q]; }
        __align__(16) ushort_t at[16], wt[16];
#pragma unroll
        for (int q = 0; q < 16; q++) {
            at[q] = f2bf(((const float*)a)[q]);
            wt[q] = f2bf(((const float*)w)[q]);
        }
        *(short8*)(&As[srow * LDSP + scol])     = *(const short8*)(at);
        *(short8*)(&As[srow * LDSP + scol + 8]) = *(const short8*)(at + 8);
        *(short8*)(&Ws[srow * LDSP + scol])     = *(const short8*)(wt);
        *(short8*)(&Ws[srow * LDSP + scol + 8]) = *(const short8*)(wt + 8);
    }
    __syncthreads();

    f32x4 acc[2][2] = {};
#pragma unroll
    for (int kk = 0; kk < 2; kk++) {
        const int kcol = kk * 32 + ((lane >> 4) << 3);
        short8 af[2], bfr[2];
#pragma unroll
        for (int i = 0; i < 2; i++)
            af[i] = *(const short8*)(&As[(wr + i * 16 + (lane & 15)) * LDSP + kcol]);
#pragma unroll
        for (int j = 0; j < 2; j++)
            bfr[j] = *(const short8*)(&Ws[(wc + j * 16 + (lane & 15)) * LDSP + kcol]);
#pragma unroll
        for (int i = 0; i < 2; i++)
#pragma unroll
            for (int j = 0; j < 2; j++)
                acc[i][j] = __builtin_amdgcn_mfma_f32_16x16x32_bf16(
                    af[i], bfr[j], acc[i][j], 0, 0, 0);
    }

#pragma unroll
    for (int j = 0; j < 2; j++) {
        int n = n0 + wc + j * 16 + (lane & 15);
        float bn = dtB[n];
#pragma unroll
        for (int i = 0; i < 2; i++) {
#pragma unroll
            for (int r = 0; r < 4; r++) {
                int m = m0 + wr + i * 16 + ((lane >> 4) << 2) + r;
                float v = acc[i][j][r] + bn;
                float sp = (v > 20.f) ? v : log1pf(__expf(v));
                delta[(size_t)m * DI + n] = sp;
            }
        }
    }
}

// ---------------------------------------------------------------------------
// Depthwise conv(4) + bias + SiLU from bf16 xzall -> ubf (bf16) only.
// dir=0: causal taps; dir=1: anti-causal (flip kept in natural order).
// ---------------------------------------------------------------------------
__global__ __launch_bounds__(256)
void conv_silu(const ushort_t* __restrict__ xzall, const float* __restrict__ convW,
               const float* __restrict__ convB, ushort_t* __restrict__ ubf, int dir)
{
    int idx = blockIdx.x * 256 + threadIdx.x;   // over M_TOT*DI/4
    int di  = (idx & (DI / 4 - 1)) << 2;
    int m   = idx >> 9;
    int b   = m >> 10, l = m & (SEQ - 1);
    const ushort_t* xb = xzall + (size_t)b * SEQ * (4 * DI) + dir * (2 * DI) + di;

    float wv[4][4];
#pragma unroll
    for (int c = 0; c < 4; c++) {
        float4 w = *(const float4*)(convW + (di + c) * 4);
        wv[c][0] = w.x; wv[c][1] = w.y; wv[c][2] = w.z; wv[c][3] = w.w;
    }
    float4 cb = *(const float4*)(convB + di);
    float acc[4] = {cb.x, cb.y, cb.z, cb.w};
#pragma unroll
    for (int j = 0; j < 4; j++) {
        int srcl = dir ? (l + 3 - j) : (l - 3 + j);
        if ((unsigned)srcl < SEQ) {
            ushort4 xv = *(const ushort4*)(xb + (size_t)srcl * (4 * DI));
            acc[0] += wv[0][j] * bf2f(xv.x);
            acc[1] += wv[1][j] * bf2f(xv.y);
            acc[2] += wv[2][j] * bf2f(xv.z);
            acc[3] += wv[3][j] * bf2f(xv.w);
        }
    }
    ushort4 o;
    o.x = f2bf(acc[0] / (1.f + __expf(-acc[0])));
    o.y = f2bf(acc[1] / (1.f + __expf(-acc[1])));
    o.z = f2bf(acc[2] / (1.f + __expf(-acc[2])));
    o.w = f2bf(acc[3] / (1.f + __expf(-acc[3])));
    *(ushort4*)(ubf + (size_t)m * DI + di) = o;
}

// ---------------------------------------------------------------------------
// Chunked selective scan (lane = d, 16 states/lane). delta fp32 coalesced,
// u read as bf16 from ubf. dir=1 runs time-reversed in natural storage.
// ---------------------------------------------------------------------------
__global__ __launch_bounds__(256)
void scan_pass1(const float* __restrict__ delta, const ushort_t* __restrict__ ubf,
                const float* __restrict__ xdbl, const float* __restrict__ Alog,
                float* __restrict__ Sb, float* __restrict__ SD, int dir)
{
    int tid = threadIdx.x, lane = tid & 63, wv = tid >> 6;
    int blk = blockIdx.x;
    int dg = blk & 7;
    int bc = blk >> 3;
    int c  = bc & (NC - 1);
    int b  = bc >> 5;
    int d  = (dg * 4 + wv) * 64 + lane;
    int t0 = dir ? (SEQ - 1 - c * LC) : (c * LC);
    int rs = dir ? -1 : 1;

    float ac2[NST];
#pragma unroll
    for (int q = 0; q < 4; q++) {
        float4 al = *(const float4*)(Alog + (size_t)d * NST + q * 4);
        ac2[q * 4 + 0] = -__expf(al.x) * LOG2E;
        ac2[q * 4 + 1] = -__expf(al.y) * LOG2E;
        ac2[q * 4 + 2] = -__expf(al.z) * LOG2E;
        ac2[q * 4 + 3] = -__expf(al.w) * LOG2E;
    }
    float h[NST];
#pragma unroll
    for (int n = 0; n < NST; n++) h[n] = 0.f;
    float sumD = 0.f;

#pragma unroll 4
    for (int l = 0; l < LC; l++) {
        int t = t0 + rs * l;
        size_t row = (size_t)b * SEQ + t;
        float dl = delta[row * DI + d];
        float uv = bf2f(ubf[row * DI + d]);
        const float* xr = xdbl + row * XPD + RNK;
        float4 Bv[4];
#pragma unroll
        for (int q = 0; q < 4; q++) Bv[q] = *(const float4*)(xr + q * 4);
        float dlu = dl * uv;
        sumD += dl;
#pragma unroll
        for (int n = 0; n < NST; n++) {
            float dA = EXP2F(dl * ac2[n]);
            h[n] = h[n] * dA + dlu * ((const float*)Bv)[n];
        }
    }

    size_t o = (size_t)c * NCH + ((size_t)b * DI + d) * NST;
#pragma unroll
    for (int q = 0; q < 4; q++)
        *(float4*)(Sb + o + q * 4) = make_float4(h[q*4], h[q*4+1], h[q*4+2], h[q*4+3]);
    SD[(size_t)c * (B_SZ * DI) + b * DI + d] = sumD;
}

__global__ __launch_bounds__(256)
void scan_combine(float* __restrict__ Sb, const float* __restrict__ SD,
                  const float* __restrict__ Alog)
{
    int i = blockIdx.x * 256 + threadIdx.x;   // chain 0..NCH-1
    int n = i & 15;
    int d = (i >> 4) & (DI - 1);
    int b = i >> 15;
    float ac2 = -__expf(Alog[(size_t)d * NST + n]) * LOG2E;
    float h = 0.f;
#pragma unroll
    for (int c = 0; c < NC; c++) {
        float s = Sb[(size_t)c * NCH + i];
        float p = EXP2F(ac2 * SD[(size_t)c * (B_SZ * DI) + b * DI + d]);
        Sb[(size_t)c * NCH + i] = h;
        h = s + p * h;
    }
}

__global__ __launch_bounds__(256)
void scan_pass2(const float* __restrict__ delta, const ushort_t* __restrict__ ubf,
                const float* __restrict__ xdbl, const ushort_t* __restrict__ xzall,
                const float* __restrict__ Alog, const float* __restrict__ Dp,
                const float* __restrict__ Hinit, ushort_t* __restrict__ ybf, int dir)
{
    int tid = threadIdx.x, lane = tid & 63, wv = tid >> 6;
    int blk = blockIdx.x;
    int dg = blk & 7;
    int bc = blk >> 3;
    int c  = bc & (NC - 1);
    int b  = bc >> 5;
    int d  = (dg * 4 + wv) * 64 + lane;
    int t0 = dir ? (SEQ - 1 - c * LC) : (c * LC);
    int rs = dir ? -1 : 1;

    float ac2[NST];
#pragma unroll
    for (int q = 0; q < 4; q++) {
        float4 al = *(const float4*)(Alog + (size_t)d * NST + q * 4);
        ac2[q * 4 + 0] = -__expf(al.x) * LOG2E;
        ac2[q * 4 + 1] = -__expf(al.y) * LOG2E;
        ac2[q * 4 + 2] = -__expf(al.z) * LOG2E;
        ac2[q * 4 + 3] = -__expf(al.w) * LOG2E;
    }
    float dp = Dp[d];
    float h[NST];
    {
        size_t o = (size_t)c * NCH + ((size_t)b * DI + d) * NST;
#pragma unroll
        for (int q = 0; q < 4; q++) {
            float4 hv = *(const float4*)(Hinit + o + q * 4);
            h[q*4] = hv.x; h[q*4+1] = hv.y; h[q*4+2] = hv.z; h[q*4+3] = hv.w;
        }
    }

#pragma unroll 4
    for (int l = 0; l < LC; l++) {
        int t = t0 + rs * l;
        size_t row = (size_t)b * SEQ + t;
        float dl = delta[row * DI + d];
        float uv = bf2f(ubf[row * DI + d]);
        const float* xr = xdbl + row * XPD + RNK;
        float4 Bv[4], Cv[4];
#pragma unroll
        for (int q = 0; q < 4; q++) {
            Bv[q] = *(const float4*)(xr + q * 4);
            Cv[q] = *(const float4*)(xr + NST + q * 4);
        }
        float dlu = dl * uv;
        float y = 0.f;
#pragma unroll
        for (int n = 0; n < NST; n++) {
            float dA = EXP2F(dl * ac2[n]);
            h[n] = h[n] * dA + dlu * ((const float*)Bv)[n];
            y += h[n] * ((const float*)Cv)[n];
        }
        float z = bf2f(xzall[row * (4 * DI) + dir * (2 * DI) + DI + d]);
        float yv = (y + uv * dp) * (z / (1.f + __expf(-z)));
        ybf[row * (2 * DI) + dir * DI + d] = f2bf(yv);
    }
}

// ---------------------------------------------------------------------------
extern "C" void kernel_launch(void* const* d_in, const int* in_sizes, int n_in,
                              void* d_out, int out_size, void* d_ws, size_t ws_size,
                              hipStream_t stream)
{
    char* wsb = (char*)d_ws;

    // layout (bytes), total 104,857,600:
    ushort_t* xzall  = (ushort_t*)wsb;                 // 33,554,432 [M x 8192] bf16
    float*    delta  = (float*)(wsb + 33554432);       // 16,777,216 [M x DI] fp32
    ushort_t* ubf    = (ushort_t*)(wsb + 50331648);    //  8,388,608 [M x DI] bf16
    ushort_t* ybf    = (ushort_t*)(wsb + 58720256);    // 16,777,216 [M x 2*DI] bf16
    ushort_t* inWcat = (ushort_t*)(wsb + 75497472);    // 16,777,216
    ushort_t* outWcat= (ushort_t*)(wsb + 92274688);    //  8,388,608 [DM x 2*DI] bf16
    ushort_t* xbf    = (ushort_t*)(wsb + 100663296);   //  4,194,304 [M x DM] bf16

    // overlays (regions dead at time of use):
    float* Sb    = (float*)inWcat;                     //  8,388,608 (after GEMM1)
    float* part2 = (float*)(wsb + 75497472 + 8388608); //  6,291,456 GEMM2 partials
    float* xdbl  = (float*)(wsb + 90177536);           //    786,432 [M x XPD]
    float* SD    = (float*)(wsb + 90963968);           //    524,288
    ushort_t* xpWbf = xbf;                             // on dead xbf (after GEMM1)
    float* part4 = (float*)xzall;                      // GEMM4 partials (after scans)

    float* out = (float*)d_out;
    dim3 blk(256);

    // --- prologue: one conversion kernel + merged GEMM1 ---
    convert_all<<<14336, blk, 0, stream>>>(
        (const float*)d_in[0], (const float*)d_in[1], (const float*)d_in[10],
        (const float*)d_in[9], (const float*)d_in[18], xbf, inWcat, outWcat);

    // xzall = x * [inW_f; inW_b]^T   [2048 x 8192], K=1024, bf16 out
    gemm_gll<true><<<dim3(8192 / 128, M_TOT / 128, 1), blk, 0, stream>>>(
        xbf, inWcat, xzall, M_TOT, 8192, DM, DM, 8192);

    for (int dir = 0; dir < 2; dir++) {
        int pb = 1 + dir * 9;
        const float* convW = (const float*)d_in[pb + 1];
        const float* convB = (const float*)d_in[pb + 2];
        const float* xpW   = (const float*)d_in[pb + 3];
        const float* dtW   = (const float*)d_in[pb + 4];
        const float* dtB   = (const float*)d_in[pb + 5];
        const float* Alog  = (const float*)d_in[pb + 6];
        const float* Dp    = (const float*)d_in[pb + 7];

        f32_to_bf16<<<(XPD * DI) / 1024, blk, 0, stream>>>(xpW, xpWbf);

        // u = silu(conv(xi)) -> ubf (bf16 only)
        conv_silu<<<(M_TOT * DI / 4) / 256, blk, 0, stream>>>(xzall, convW, convB,
                                                              ubf, dir);

        // xdbl = u * xpW^T  [2048 x 96], K=2048, split-K=8 + reduce
        gemm2_splitk<<<dim3(2, M_TOT / 64, 8), blk, 0, stream>>>(
            ubf, xpWbf, part2, M_TOT, XPD, DI, DI / 8);
        xdbl_reduce<<<(M_TOT * XPD / 4) / 256, blk, 0, stream>>>(part2, xdbl);

        // delta = softplus(dt*dtW^T + dtB)
        delta_gemm<<<dim3(DI / 64, M_TOT / 64), blk, 0, stream>>>(xdbl, dtW, dtB,
                                                                  delta);

        // chunked exact scan (time-reversed for dir=1)
        scan_pass1<<<B_SZ * NC * 8, blk, 0, stream>>>(delta, ubf, xdbl, Alog,
                                                      Sb, SD, dir);
        scan_combine<<<NCH / 256, blk, 0, stream>>>(Sb, SD, Alog);
        scan_pass2<<<B_SZ * NC * 8, blk, 0, stream>>>(delta, ubf, xdbl, xzall,
                                                      Alog, Dp, Sb, ybf, dir);
    }

    // out = 0.5 * [y_f | y_b] * [outW_f | outW_b]^T : K=4096, splitK=4
    gemm_gll<false><<<dim3(DM / 128, M_TOT / 128, 4), blk, 0, stream>>>(
        ybf, outWcat, part4, M_TOT, DM, 2 * DI, DI / 2, DM);
    reduce4<<<(M_TOT * DM / 4) / 256, blk, 0, stream>>>(part4, out);
}

// Round 9
// 357.767 us; speedup vs baseline: 2.0758x; 1.1544x over previous
//
#include <hip/hip_runtime.h>
#include <math.h>

#define B_SZ 2
#define SEQ  1024
#define DM   1024
#define DI   2048
#define NST  16
#define RNK  64
#define XPD  96            // RNK + 2*NST
#define M_TOT (B_SZ*SEQ)   // 2048
#define NC   32            // scan chunks
#define LC   (SEQ/NC)      // 32 steps per chunk
#define NCH  65536         // total chains = B_SZ*DI*NST

typedef unsigned short ushort_t;
typedef __attribute__((ext_vector_type(8))) short short8;   // 8 bf16 = 4 VGPRs
typedef __attribute__((ext_vector_type(4))) float f32x4;

#if __has_builtin(__builtin_amdgcn_exp2f)
#define EXP2F __builtin_amdgcn_exp2f
#else
#define EXP2F exp2f
#endif
#define LOG2E 1.44269504f

__device__ __forceinline__ ushort_t f2bf(float f) {
    unsigned u = __float_as_uint(f);
    u += 0x7fff + ((u >> 16) & 1);           // round-to-nearest-even
    return (ushort_t)(u >> 16);
}
__device__ __forceinline__ float bf2f(ushort_t v) {
    return __uint_as_float(((unsigned)v) << 16);
}

// ---------------------------------------------------------------------------
// One-shot prologue conversion (segmented by blockIdx):
//   x | inW_f | inW_b | outW_f (strided) | outW_b (strided) | xpW_f | xpW_b
//   blocks: 2048 | 4096 | 4096 | 2048 | 2048 | 192 | 192 = 14720
// ---------------------------------------------------------------------------
__global__ __launch_bounds__(256)
void convert_all(const float* __restrict__ x,
                 const float* __restrict__ inWf, const float* __restrict__ inWb,
                 const float* __restrict__ outWf, const float* __restrict__ outWb,
                 const float* __restrict__ xpWf, const float* __restrict__ xpWb,
                 ushort_t* __restrict__ xbf, ushort_t* __restrict__ inWcat,
                 ushort_t* __restrict__ outWcat, ushort_t* __restrict__ xpWcat)
{
    int bid = blockIdx.x;
    const float* src; ushort_t* dst; int rel; int strided = 0;
    if (bid < 2048)       { rel = bid;         src = x;     dst = xbf; }
    else if (bid < 6144)  { rel = bid - 2048;  src = inWf;  dst = inWcat; }
    else if (bid < 10240) { rel = bid - 6144;  src = inWb;  dst = inWcat + (size_t)2 * DI * DM; }
    else if (bid < 12288) { rel = bid - 10240; src = outWf; dst = outWcat;      strided = 1; }
    else if (bid < 14336) { rel = bid - 12288; src = outWb; dst = outWcat + DI; strided = 1; }
    else if (bid < 14528) { rel = bid - 14336; src = xpWf;  dst = xpWcat; }
    else                  { rel = bid - 14528; src = xpWb;  dst = xpWcat + (size_t)XPD * DI; }
    int i = rel * 256 + threadIdx.x;
    float4 v = ((const float4*)src)[i];
    ushort4 o;
    o.x = f2bf(v.x); o.y = f2bf(v.y); o.z = f2bf(v.z); o.w = f2bf(v.w);
    if (!strided) {
        ((ushort4*)dst)[i] = o;
    } else {
        int row = i >> 9;                 // rowLen4 = DI/4 = 512
        int c4  = (i - (row << 9)) << 2;
        *(ushort4*)(dst + (size_t)row * (2 * DI) + c4) = o;
    }
}

// ---------------------------------------------------------------------------
// m97-style bf16 MFMA NT GEMM, 128x128 tile, BK=64, global_load_lds staging,
// XOR-swizzled unpadded LDS. OUT_BF16: D bf16 [M x ldD]; else fp32 partials.
// ---------------------------------------------------------------------------
__device__ __forceinline__ void load_lds16(const ushort_t* g, ushort_t* l) {
    __builtin_amdgcn_global_load_lds(
        (const __attribute__((address_space(1))) void*)g,
        (__attribute__((address_space(3))) void*)l, 16, 0, 0);
}

template<bool OUT_BF16>
__global__ __launch_bounds__(256)
void gemm_gll(const ushort_t* __restrict__ A, const ushort_t* __restrict__ W,
              void* __restrict__ D, int M, int N, int K, int kLen, int ldD)
{
    __shared__ __align__(16) ushort_t As[128 * 64];
    __shared__ __align__(16) ushort_t Ws[128 * 64];
    const int t    = threadIdx.x;
    const int lane = t & 63;
    const int wave = t >> 6;
    const int wr   = (wave >> 1) * 64;
    const int wc   = (wave & 1) * 64;

    const int m0 = blockIdx.y * 128;
    const int n0 = blockIdx.x * 128;
    const int kStart = blockIdx.z * kLen;

    const int srow   = lane >> 3;
    const int gchunk = (lane & 7) ^ srow;

    f32x4 acc[4][4] = {};

    for (int k0 = kStart; k0 < kStart + kLen; k0 += 64) {
#pragma unroll
        for (int it = 0; it < 4; it++) {
            const int rb = wave * 32 + it * 8;
            load_lds16(A + (size_t)(m0 + rb + srow) * K + k0 + gchunk * 8,
                       As + rb * 64);
            load_lds16(W + (size_t)(n0 + rb + srow) * K + k0 + gchunk * 8,
                       Ws + rb * 64);
        }
        __syncthreads();
#pragma unroll
        for (int kk = 0; kk < 2; kk++) {
            const int kc = kk * 4 + (lane >> 4);
            short8 af[4], bf[4];
#pragma unroll
            for (int i = 0; i < 4; i++) {
                int r = wr + i * 16 + (lane & 15);
                af[i] = *(const short8*)(As + r * 64 + ((kc ^ (r & 7)) << 3));
            }
#pragma unroll
            for (int j = 0; j < 4; j++) {
                int r = wc + j * 16 + (lane & 15);
                bf[j] = *(const short8*)(Ws + r * 64 + ((kc ^ (r & 7)) << 3));
            }
#pragma unroll
            for (int i = 0; i < 4; i++)
#pragma unroll
                for (int j = 0; j < 4; j++)
                    acc[i][j] = __builtin_amdgcn_mfma_f32_16x16x32_bf16(
                        af[i], bf[j], acc[i][j], 0, 0, 0);
        }
        __syncthreads();
    }

    if (OUT_BF16) {
        ushort_t* Dp = (ushort_t*)D;
#pragma unroll
        for (int i = 0; i < 4; i++)
#pragma unroll
            for (int r = 0; r < 4; r++) {
                int m = m0 + wr + i * 16 + ((lane >> 4) << 2) + r;
#pragma unroll
                for (int j = 0; j < 4; j++) {
                    int n = n0 + wc + j * 16 + (lane & 15);
                    Dp[(size_t)m * ldD + n] = f2bf(acc[i][j][r]);
                }
            }
    } else {
        float* Dp = (float*)D + (size_t)blockIdx.z * M * ldD;
#pragma unroll
        for (int i = 0; i < 4; i++)
#pragma unroll
            for (int r = 0; r < 4; r++) {
                int m = m0 + wr + i * 16 + ((lane >> 4) << 2) + r;
#pragma unroll
                for (int j = 0; j < 4; j++) {
                    int n = n0 + wc + j * 16 + (lane & 15);
                    Dp[(size_t)m * ldD + n] = acc[i][j][r];
                }
            }
    }
}

// out = 0.5 * (P0 + P1 + P2 + P3)
__global__ __launch_bounds__(256)
void reduce4(const float* __restrict__ P, float* __restrict__ out)
{
    int i = blockIdx.x * 256 + threadIdx.x;
    const size_t S = (size_t)M_TOT * DM / 4;
    float4 a = ((const float4*)P)[i];
    float4 b = ((const float4*)P)[i + S];
    float4 c = ((const float4*)P)[i + 2 * S];
    float4 d = ((const float4*)P)[i + 3 * S];
    float4 o;
    o.x = 0.5f * (a.x + b.x + c.x + d.x);
    o.y = 0.5f * (a.y + b.y + c.y + d.y);
    o.z = 0.5f * (a.z + b.z + c.z + d.z);
    o.w = 0.5f * (a.w + b.w + c.w + d.w);
    ((float4*)out)[i] = o;
}

// ---------------------------------------------------------------------------
// GEMM2 both-dir split-K: grid (2, M/64, 16); z = dir*8 + kz.
// P[dir][kz] = ubf[dir] * xpW[dir]^T over K-slice. 64x64 tile, N=96 masked.
// ---------------------------------------------------------------------------
#define LDSP 72

__global__ __launch_bounds__(256)
void gemm2_splitk2(const ushort_t* __restrict__ ubf, const ushort_t* __restrict__ xpWcat,
                   float* __restrict__ P)
{
    const int dir = blockIdx.z >> 3;
    const int kz  = blockIdx.z & 7;
    const ushort_t* A = ubf + (size_t)dir * M_TOT * DI;
    const ushort_t* W = xpWcat + (size_t)dir * XPD * DI;
    const int K = DI, N = XPD;

    __shared__ __align__(16) ushort_t As[64 * LDSP];
    __shared__ __align__(16) ushort_t Ws[64 * LDSP];
    const int t    = threadIdx.x;
    const int lane = t & 63;
    const int wave = t >> 6;
    const int wr   = (wave >> 1) * 32;
    const int wc   = (wave & 1) * 32;

    f32x4 acc[2][2] = {};

    const int m0 = blockIdx.y * 64;
    const int n0 = blockIdx.x * 64;
    const int kStart = kz * (DI / 8);
    const int srow = t >> 3;
    const int scol = (t & 7) << 3;

    for (int k0 = kStart; k0 < kStart + DI / 8; k0 += 64) {
        {
            int r = srow;
            short8 v = *(const short8*)(A + (size_t)(m0 + r) * K + k0 + scol);
            *(short8*)(&As[r * LDSP + scol]) = v;
            int r2 = 32 + srow;
            short8 v2 = *(const short8*)(A + (size_t)(m0 + r2) * K + k0 + scol);
            *(short8*)(&As[r2 * LDSP + scol]) = v2;
            int wn = n0 + r;
            short8 wv = {};
            if (wn < N) wv = *(const short8*)(W + (size_t)wn * K + k0 + scol);
            *(short8*)(&Ws[r * LDSP + scol]) = wv;
            int wn2 = n0 + r2;
            short8 wv2 = {};
            if (wn2 < N) wv2 = *(const short8*)(W + (size_t)wn2 * K + k0 + scol);
            *(short8*)(&Ws[r2 * LDSP + scol]) = wv2;
        }
        __syncthreads();
#pragma unroll
        for (int kk = 0; kk < 2; kk++) {
            const int kcol = kk * 32 + ((lane >> 4) << 3);
            short8 af[2], bfr[2];
#pragma unroll
            for (int i = 0; i < 2; i++)
                af[i] = *(const short8*)(&As[(wr + i * 16 + (lane & 15)) * LDSP + kcol]);
#pragma unroll
            for (int j = 0; j < 2; j++)
                bfr[j] = *(const short8*)(&Ws[(wc + j * 16 + (lane & 15)) * LDSP + kcol]);
#pragma unroll
            for (int i = 0; i < 2; i++)
#pragma unroll
                for (int j = 0; j < 2; j++)
                    acc[i][j] = __builtin_amdgcn_mfma_f32_16x16x32_bf16(
                        af[i], bfr[j], acc[i][j], 0, 0, 0);
        }
        __syncthreads();
    }

    float* Pz = P + ((size_t)dir * 8 + kz) * M_TOT * XPD;
#pragma unroll
    for (int i = 0; i < 2; i++)
#pragma unroll
        for (int r = 0; r < 4; r++) {
            int m = m0 + wr + i * 16 + ((lane >> 4) << 2) + r;
#pragma unroll
            for (int j = 0; j < 2; j++) {
                int n = n0 + wc + j * 16 + (lane & 15);
                if (n < N) Pz[(size_t)m * XPD + n] = acc[i][j][r];
            }
        }
}

// xdbl[dir] = sum of 8 partials; grid 384 (192 per dir)
__global__ __launch_bounds__(256)
void xdbl_reduce2(const float* __restrict__ P, float* __restrict__ xdbl)
{
    int bid = blockIdx.x;
    int dir = bid >= 192;
    int i = (bid - dir * 192) * 256 + threadIdx.x;   // float4 over M*XPD/4
    const size_t S = (size_t)M_TOT * XPD / 4;
    const float4* Pd = (const float4*)(P + (size_t)dir * 8 * M_TOT * XPD);
    float4 s = Pd[i];
#pragma unroll
    for (int z = 1; z < 8; z++) {
        float4 v = Pd[i + z * S];
        s.x += v.x; s.y += v.y; s.z += v.z; s.w += v.w;
    }
    ((float4*)(xdbl + (size_t)dir * M_TOT * XPD))[i] = s;
}

// ---------------------------------------------------------------------------
// delta[dir] = softplus(dt * dtW[dir]^T + dtB[dir]) -> bf16 [M x DI]
// grid (DI/64, M/64, 2); single-K-tile MFMA GEMM.
// ---------------------------------------------------------------------------
__global__ __launch_bounds__(256)
void delta_gemm2(const float* __restrict__ xdbl,
                 const float* __restrict__ dtWf, const float* __restrict__ dtWb,
                 const float* __restrict__ dtBf, const float* __restrict__ dtBb,
                 ushort_t* __restrict__ deltab)
{
    const int dir = blockIdx.z;
    const float* xd  = xdbl + (size_t)dir * M_TOT * XPD;
    const float* dtW = dir ? dtWb : dtWf;
    const float* dtB = dir ? dtBb : dtBf;
    ushort_t* delta  = deltab + (size_t)dir * M_TOT * DI;

    __shared__ __align__(16) ushort_t As[64 * LDSP];
    __shared__ __align__(16) ushort_t Ws[64 * LDSP];
    const int t    = threadIdx.x;
    const int lane = t & 63;
    const int wave = t >> 6;
    const int wr   = (wave >> 1) * 32;
    const int wc   = (wave & 1) * 32;

    const int m0 = blockIdx.y * 64;
    const int n0 = blockIdx.x * 64;
    const int srow = t >> 2;            // 0..63
    const int scol = (t & 3) << 4;      // 0,16,32,48

    {
        const float* ap = xd  + (size_t)(m0 + srow) * XPD + scol;
        const float* wp = dtW + (size_t)(n0 + srow) * RNK + scol;
        float4 a[4], w[4];
#pragma unroll
        for (int q = 0; q < 4; q++) { a[q] = ((const float4*)ap)[q]; w[q] = ((const float4*)wp)[q]; }
        __align__(16) ushort_t at[16], wt[16];
#pragma unroll
        for (int q = 0; q < 16; q++) {
            at[q] = f2bf(((const float*)a)[q]);
            wt[q] = f2bf(((const float*)w)[q]);
        }
        *(short8*)(&As[srow * LDSP + scol])     = *(const short8*)(at);
        *(short8*)(&As[srow * LDSP + scol + 8]) = *(const short8*)(at + 8);
        *(short8*)(&Ws[srow * LDSP + scol])     = *(const short8*)(wt);
        *(short8*)(&Ws[srow * LDSP + scol + 8]) = *(const short8*)(wt + 8);
    }
    __syncthreads();

    f32x4 acc[2][2] = {};
#pragma unroll
    for (int kk = 0; kk < 2; kk++) {
        const int kcol = kk * 32 + ((lane >> 4) << 3);
        short8 af[2], bfr[2];
#pragma unroll
        for (int i = 0; i < 2; i++)
            af[i] = *(const short8*)(&As[(wr + i * 16 + (lane & 15)) * LDSP + kcol]);
#pragma unroll
        for (int j = 0; j < 2; j++)
            bfr[j] = *(const short8*)(&Ws[(wc + j * 16 + (lane & 15)) * LDSP + kcol]);
#pragma unroll
        for (int i = 0; i < 2; i++)
#pragma unroll
            for (int j = 0; j < 2; j++)
                acc[i][j] = __builtin_amdgcn_mfma_f32_16x16x32_bf16(
                    af[i], bfr[j], acc[i][j], 0, 0, 0);
    }

#pragma unroll
    for (int j = 0; j < 2; j++) {
        int n = n0 + wc + j * 16 + (lane & 15);
        float bn = dtB[n];
#pragma unroll
        for (int i = 0; i < 2; i++) {
#pragma unroll
            for (int r = 0; r < 4; r++) {
                int m = m0 + wr + i * 16 + ((lane >> 4) << 2) + r;
                float v = acc[i][j][r] + bn;
                float sp = (v > 20.f) ? v : log1pf(__expf(v));
                delta[(size_t)m * DI + n] = f2bf(sp);
            }
        }
    }
}

// ---------------------------------------------------------------------------
// Depthwise conv(4) + bias + SiLU, both dirs: grid 8192 (4096 per dir).
// dir=0 causal, dir=1 anti-causal (natural order). -> ubf[dir] bf16.
// ---------------------------------------------------------------------------
__global__ __launch_bounds__(256)
void conv_silu2(const ushort_t* __restrict__ xzall,
                const float* __restrict__ convWf, const float* __restrict__ convWb,
                const float* __restrict__ convBf, const float* __restrict__ convBb,
                ushort_t* __restrict__ ubf)
{
    int bid = blockIdx.x;
    int dir = bid >> 12;                          // 4096 blocks per dir
    int idx = (bid & 4095) * 256 + threadIdx.x;   // over M_TOT*DI/4
    const float* convW = dir ? convWb : convWf;
    const float* convB = dir ? convBb : convBf;
    int di  = (idx & (DI / 4 - 1)) << 2;
    int m   = idx >> 9;
    int b   = m >> 10, l = m & (SEQ - 1);
    const ushort_t* xb = xzall + (size_t)b * SEQ * (4 * DI) + dir * (2 * DI) + di;

    float wv[4][4];
#pragma unroll
    for (int c = 0; c < 4; c++) {
        float4 w = *(const float4*)(convW + (di + c) * 4);
        wv[c][0] = w.x; wv[c][1] = w.y; wv[c][2] = w.z; wv[c][3] = w.w;
    }
    float4 cb = *(const float4*)(convB + di);
    float acc[4] = {cb.x, cb.y, cb.z, cb.w};
#pragma unroll
    for (int j = 0; j < 4; j++) {
        int srcl = dir ? (l + 3 - j) : (l - 3 + j);
        if ((unsigned)srcl < SEQ) {
            ushort4 xv = *(const ushort4*)(xb + (size_t)srcl * (4 * DI));
            acc[0] += wv[0][j] * bf2f(xv.x);
            acc[1] += wv[1][j] * bf2f(xv.y);
            acc[2] += wv[2][j] * bf2f(xv.z);
            acc[3] += wv[3][j] * bf2f(xv.w);
        }
    }
    ushort4 o;
    o.x = f2bf(acc[0] / (1.f + __expf(-acc[0])));
    o.y = f2bf(acc[1] / (1.f + __expf(-acc[1])));
    o.z = f2bf(acc[2] / (1.f + __expf(-acc[2])));
    o.w = f2bf(acc[3] / (1.f + __expf(-acc[3])));
    *(ushort4*)(ubf + (size_t)dir * M_TOT * DI + (size_t)m * DI + di) = o;
}

// ---------------------------------------------------------------------------
// Chunked selective scan, both dirs (lane = d, 16 states/lane).
// grid 1024 = 512/dir; within dir: dg = blk&7, c = (blk>>3)&31, b = blk>>8.
// ---------------------------------------------------------------------------
__global__ __launch_bounds__(256)
void scan_pass1_2(const ushort_t* __restrict__ deltab, const ushort_t* __restrict__ ubf,
                  const float* __restrict__ xdbl,
                  const float* __restrict__ Alogf, const float* __restrict__ Alogb,
                  float* __restrict__ Sb, float* __restrict__ SD)
{
    int tid = threadIdx.x, lane = tid & 63, wv = tid >> 6;
    int blk = blockIdx.x;
    int dir = blk >> 9;
    blk &= 511;
    int dg = blk & 7;
    int bc = blk >> 3;
    int c  = bc & (NC - 1);
    int b  = bc >> 5;
    int d  = (dg * 4 + wv) * 64 + lane;
    int t0 = dir ? (SEQ - 1 - c * LC) : (c * LC);
    int rs = dir ? -1 : 1;

    const float* Alog = dir ? Alogb : Alogf;
    const ushort_t* dl_p = deltab + (size_t)dir * M_TOT * DI;
    const ushort_t* u_p  = ubf    + (size_t)dir * M_TOT * DI;
    const float*    xd   = xdbl   + (size_t)dir * M_TOT * XPD;
    float* Sbd = Sb + (size_t)dir * NC * NCH;
    float* SDd = SD + (size_t)dir * NC * B_SZ * DI;

    float ac2[NST];
#pragma unroll
    for (int q = 0; q < 4; q++) {
        float4 al = *(const float4*)(Alog + (size_t)d * NST + q * 4);
        ac2[q * 4 + 0] = -__expf(al.x) * LOG2E;
        ac2[q * 4 + 1] = -__expf(al.y) * LOG2E;
        ac2[q * 4 + 2] = -__expf(al.z) * LOG2E;
        ac2[q * 4 + 3] = -__expf(al.w) * LOG2E;
    }
    float h[NST];
#pragma unroll
    for (int n = 0; n < NST; n++) h[n] = 0.f;
    float sumD = 0.f;

#pragma unroll 4
    for (int l = 0; l < LC; l++) {
        int t = t0 + rs * l;
        size_t row = (size_t)b * SEQ + t;
        float dl = bf2f(dl_p[row * DI + d]);
        float uv = bf2f(u_p[row * DI + d]);
        const float* xr = xd + row * XPD + RNK;
        float4 Bv[4];
#pragma unroll
        for (int q = 0; q < 4; q++) Bv[q] = *(const float4*)(xr + q * 4);
        float dlu = dl * uv;
        sumD += dl;
#pragma unroll
        for (int n = 0; n < NST; n++) {
            float dA = EXP2F(dl * ac2[n]);
            h[n] = h[n] * dA + dlu * ((const float*)Bv)[n];
        }
    }

    size_t o = (size_t)c * NCH + ((size_t)b * DI + d) * NST;
#pragma unroll
    for (int q = 0; q < 4; q++)
        *(float4*)(Sbd + o + q * 4) = make_float4(h[q*4], h[q*4+1], h[q*4+2], h[q*4+3]);
    SDd[(size_t)c * (B_SZ * DI) + b * DI + d] = sumD;
}

__global__ __launch_bounds__(256)
void scan_combine2(float* __restrict__ Sb, const float* __restrict__ SD,
                   const float* __restrict__ Alogf, const float* __restrict__ Alogb)
{
    int gid = blockIdx.x * 256 + threadIdx.x;   // 0 .. 2*NCH-1
    int dir = gid >= NCH;
    int i = gid - dir * NCH;
    int n = i & 15;
    int d = (i >> 4) & (DI - 1);
    int b = i >> 15;
    const float* Alog = dir ? Alogb : Alogf;
    float* Sbd = Sb + (size_t)dir * NC * NCH;
    const float* SDd = SD + (size_t)dir * NC * B_SZ * DI;
    float ac2 = -__expf(Alog[(size_t)d * NST + n]) * LOG2E;
    float h = 0.f;
#pragma unroll
    for (int c = 0; c < NC; c++) {
        float s = Sbd[(size_t)c * NCH + i];
        float p = EXP2F(ac2 * SDd[(size_t)c * (B_SZ * DI) + b * DI + d]);
        Sbd[(size_t)c * NCH + i] = h;
        h = s + p * h;
    }
}

__global__ __launch_bounds__(256)
void scan_pass2_2(const ushort_t* __restrict__ deltab, const ushort_t* __restrict__ ubf,
                  const float* __restrict__ xdbl, const ushort_t* __restrict__ xzall,
                  const float* __restrict__ Alogf, const float* __restrict__ Alogb,
                  const float* __restrict__ Dpf, const float* __restrict__ Dpb,
                  const float* __restrict__ Hinit, ushort_t* __restrict__ ybf)
{
    int tid = threadIdx.x, lane = tid & 63, wv = tid >> 6;
    int blk = blockIdx.x;
    int dir = blk >> 9;
    blk &= 511;
    int dg = blk & 7;
    int bc = blk >> 3;
    int c  = bc & (NC - 1);
    int b  = bc >> 5;
    int d  = (dg * 4 + wv) * 64 + lane;
    int t0 = dir ? (SEQ - 1 - c * LC) : (c * LC);
    int rs = dir ? -1 : 1;

    const float* Alog = dir ? Alogb : Alogf;
    const float* Dpp  = dir ? Dpb : Dpf;
    const ushort_t* dl_p = deltab + (size_t)dir * M_TOT * DI;
    const ushort_t* u_p  = ubf    + (size_t)dir * M_TOT * DI;
    const float*    xd   = xdbl   + (size_t)dir * M_TOT * XPD;
    const float*    Hin  = Hinit  + (size_t)dir * NC * NCH;

    float ac2[NST];
#pragma unroll
    for (int q = 0; q < 4; q++) {
        float4 al = *(const float4*)(Alog + (size_t)d * NST + q * 4);
        ac2[q * 4 + 0] = -__expf(al.x) * LOG2E;
        ac2[q * 4 + 1] = -__expf(al.y) * LOG2E;
        ac2[q * 4 + 2] = -__expf(al.z) * LOG2E;
        ac2[q * 4 + 3] = -__expf(al.w) * LOG2E;
    }
    float dp = Dpp[d];
    float h[NST];
    {
        size_t o = (size_t)c * NCH + ((size_t)b * DI + d) * NST;
#pragma unroll
        for (int q = 0; q < 4; q++) {
            float4 hv = *(const float4*)(Hin + o + q * 4);
            h[q*4] = hv.x; h[q*4+1] = hv.y; h[q*4+2] = hv.z; h[q*4+3] = hv.w;
        }
    }

#pragma unroll 4
    for (int l = 0; l < LC; l++) {
        int t = t0 + rs * l;
        size_t row = (size_t)b * SEQ + t;
        float dl = bf2f(dl_p[row * DI + d]);
        float uv = bf2f(u_p[row * DI + d]);
        const float* xr = xd + row * XPD + RNK;
        float4 Bv[4], Cv[4];
#pragma unroll
        for (int q = 0; q < 4; q++) {
            Bv[q] = *(const float4*)(xr + q * 4);
            Cv[q] = *(const float4*)(xr + NST + q * 4);
        }
        float dlu = dl * uv;
        float y = 0.f;
#pragma unroll
        for (int n = 0; n < NST; n++) {
            float dA = EXP2F(dl * ac2[n]);
            h[n] = h[n] * dA + dlu * ((const float*)Bv)[n];
            y += h[n] * ((const float*)Cv)[n];
        }
        float z = bf2f(xzall[row * (4 * DI) + dir * (2 * DI) + DI + d]);
        float yv = (y + uv * dp) * (z / (1.f + __expf(-z)));
        ybf[row * (2 * DI) + dir * DI + d] = f2bf(yv);
    }
}

// ---------------------------------------------------------------------------
extern "C" void kernel_launch(void* const* d_in, const int* in_sizes, int n_in,
                              void* d_out, int out_size, void* d_ws, size_t ws_size,
                              hipStream_t stream)
{
    char* wsb = (char*)d_ws;

    // layout (bytes), total 115,605,504:
    ushort_t* xzall  = (ushort_t*)wsb;                 // 33,554,432 [M x 8192] bf16
    ushort_t* ybf    = (ushort_t*)(wsb + 33554432);    // 16,777,216 [M x 2*DI] bf16
    ushort_t* inWcat = (ushort_t*)(wsb + 50331648);    // 16,777,216
    ushort_t* outWcat= (ushort_t*)(wsb + 67108864);    //  8,388,608 [DM x 2*DI] bf16
    ushort_t* xbf    = (ushort_t*)(wsb + 75497472);    //  4,194,304 [M x DM] bf16
    ushort_t* xpWcat = (ushort_t*)(wsb + 79691776);    //    786,432 [2][XPD x DI] bf16
    ushort_t* ubf    = (ushort_t*)(wsb + 80478208);    // 16,777,216 [2][M x DI] bf16
    ushort_t* deltab = (ushort_t*)(wsb + 97255424);    // 16,777,216 [2][M x DI] bf16
    float*    xdbl   = (float*)(wsb + 114032640);      //  1,572,864 [2][M x XPD] fp32

    // overlays (dead regions):
    float* Sb    = (float*)inWcat;                     // 16,777,216 [2][NC x NCH] (after GEMM1)
    float* SD    = (float*)xbf;                        //  1,048,576 [2][...]      (after GEMM1)
    float* part2 = (float*)deltab;                     // 12,582,912 [2][8 x M x XPD] (pre-delta)
    float* part4 = (float*)xzall;                      // 33,554,432 (after scans)

    float* out = (float*)d_out;
    dim3 blk(256);

    // 1. prologue conversions (single dispatch)
    convert_all<<<14720, blk, 0, stream>>>(
        (const float*)d_in[0], (const float*)d_in[1], (const float*)d_in[10],
        (const float*)d_in[9], (const float*)d_in[18],
        (const float*)d_in[4], (const float*)d_in[13],
        xbf, inWcat, outWcat, xpWcat);

    // 2. xzall = x * [inW_f; inW_b]^T   [2048 x 8192], K=1024, bf16 out
    gemm_gll<true><<<dim3(8192 / 128, M_TOT / 128, 1), blk, 0, stream>>>(
        xbf, inWcat, xzall, M_TOT, 8192, DM, DM, 8192);

    // 3. u = silu(conv(xi)), both dirs (4096 blocks per dir)
    conv_silu2<<<8192, blk, 0, stream>>>(xzall,
        (const float*)d_in[2], (const float*)d_in[11],
        (const float*)d_in[3], (const float*)d_in[12], ubf);

    // 4. xdbl partials, both dirs, split-K=8
    gemm2_splitk2<<<dim3(2, M_TOT / 64, 16), blk, 0, stream>>>(ubf, xpWcat, part2);

    // 5. xdbl = sum partials, both dirs
    xdbl_reduce2<<<384, blk, 0, stream>>>(part2, xdbl);

    // 6. delta = softplus(dt*dtW^T + dtB) -> bf16, both dirs
    delta_gemm2<<<dim3(DI / 64, M_TOT / 64, 2), blk, 0, stream>>>(
        xdbl, (const float*)d_in[5], (const float*)d_in[14],
        (const float*)d_in[6], (const float*)d_in[15], deltab);

    // 7-9. chunked exact scan, both dirs
    scan_pass1_2<<<1024, blk, 0, stream>>>(deltab, ubf, xdbl,
        (const float*)d_in[7], (const float*)d_in[16], Sb, SD);
    scan_combine2<<<2 * NCH / 256, blk, 0, stream>>>(Sb, SD,
        (const float*)d_in[7], (const float*)d_in[16]);
    scan_pass2_2<<<1024, blk, 0, stream>>>(deltab, ubf, xdbl, xzall,
        (const float*)d_in[7], (const float*)d_in[16],
        (const float*)d_in[8], (const float*)d_in[17], Sb, ybf);

    // 10. out = 0.5 * [y_f | y_b] * [outW_f | outW_b]^T : K=4096, splitK=4
    gemm_gll<false><<<dim3(DM / 128, M_TOT / 128, 4), blk, 0, stream>>>(
        ybf, outWcat, part4, M_TOT, DM, 2 * DI, DI / 2, DM);

    // 11. final reduce
    reduce4<<<(M_TOT * DM / 4) / 256, blk, 0, stream>>>(part4, out);
}